// Round 16
// baseline (185.862 us; speedup 1.0000x reference)
//
#include <hip/hip_runtime.h>
#include <cstdint>

using u16    = unsigned short;
using u32    = unsigned int;
using bf16x8 = __attribute__((ext_vector_type(8))) __bf16;
using f32x4  = __attribute__((ext_vector_type(4))) float;

__device__ __forceinline__ u16 f2bf(float f) {
    u32 u = __builtin_bit_cast(u32, f);
    u += 0x7FFFu + ((u >> 16) & 1u);
    return (u16)(u >> 16);
}
__device__ __forceinline__ float bf2f(u16 u) {
    return __builtin_bit_cast(float, (u32)u << 16);
}
__device__ __forceinline__ u32 pk_bf16(float a, float b) {
    u32 r;
    asm("v_cvt_pk_bf16_f32 %0, %1, %2" : "=v"(r) : "v"(a), "v"(b));
    return r;
}
// raw 2^x (v_exp_f32 IS exp2 in hardware; single TRANS op, no libm path)
__device__ __forceinline__ float hw_exp2(float x) {
    float r;
    asm("v_exp_f32 %0, %1" : "=v"(r) : "v"(x));
    return r;
}
__device__ __forceinline__ void load_lds16(const u16* g, u16* l) {
    __builtin_amdgcn_global_load_lds((const __attribute__((address_space(1))) void*)g,
                                     (__attribute__((address_space(3))) void*)l, 16, 0, 0);
}

// ---------------- fused f32 -> bf16 convert for x and y ----------------
__global__ __launch_bounds__(256) void cvt2_kernel(const float* __restrict__ a,
                                                   const float* __restrict__ b,
                                                   u16* __restrict__ oa,
                                                   u16* __restrict__ ob)
{
    const int bid = blockIdx.x;
    const float* in = bid < 2048 ? a : b;
    u16* out = bid < 2048 ? oa : ob;
    int i = ((bid & 2047) * 256 + threadIdx.x) * 4;
    float4 v = *(const float4*)(in + i);
    uint2 o;
    o.x = (u32)f2bf(v.x) | ((u32)f2bf(v.y) << 16);
    o.y = (u32)f2bf(v.z) | ((u32)f2bf(v.w) << 16);
    *(uint2*)(out + i) = o;
}

// ---------------- weight transpose + convert (flat exact grid: 4608 blocks) ----------------
__global__ __launch_bounds__(256) void wtrans_kernel(const float* __restrict__ Wq,
                                                     const float* __restrict__ Wk,
                                                     const float* __restrict__ Wv,
                                                     const float* __restrict__ Wo,
                                                     const float* __restrict__ W1,
                                                     const float* __restrict__ W2,
                                                     u16* __restrict__ wt)
{
    const int gid = blockIdx.x;
    const float* src; u16* dst; int K = 512, N = 512; int n0, k0;
    if (gid < 2560) {
        int z = gid >> 8, tid = gid & 255;
        switch (z) {
            case 0: case 1: case 2: case 3:
                src = Wq + (size_t)z * 262144;        dst = wt + (size_t)z * 262144;            break;
            case 4: case 5: case 6: case 7:
                src = Wk + (size_t)(z - 4) * 262144;  dst = wt + 1048576 + (size_t)(z - 4) * 262144; break;
            case 8: src = Wv + 3 * 262144;  dst = wt + 2097152; break;
            default: src = Wo + 3 * 262144; dst = wt + 2359296; break;
        }
        n0 = (tid & 15) * 32; k0 = (tid >> 4) * 32;
    } else if (gid < 3584) {
        int tid = gid - 2560;
        src = W1 + 3 * 1048576; dst = wt + 2621440; K = 512; N = 2048;
        n0 = (tid & 63) * 32; k0 = (tid >> 6) * 32;
    } else {
        int tid = gid - 3584;
        src = W2 + 3 * 1048576; dst = wt + 3670016; K = 2048; N = 512;
        n0 = (tid & 15) * 32; k0 = (tid >> 4) * 32;
    }
    __shared__ float tile[32][33];
    int tx = threadIdx.x, ty = threadIdx.y;
    #pragma unroll
    for (int i = 0; i < 4; i++) {
        int r = ty + i * 8;
        tile[r][tx] = src[(size_t)(k0 + r) * N + n0 + tx];
    }
    __syncthreads();
    #pragma unroll
    for (int i = 0; i < 4; i++) {
        int rn = ty + i * 8;
        dst[(size_t)(n0 + rn) * K + k0 + tx] = f2bf(tile[tx][rn]);
    }
}

// ---------------- BK=32 double-buffered GEMM core (m97 shape + 2-phase + XOR swizzle) ----------------
template<int BNF>
__device__ __forceinline__ void gemm_core32(const u16* __restrict__ A,
                                            const u16* __restrict__ BT,
                                            int K, int m0, int n0,
                                            u16 (*As)[32], u16 (*Bs)[32],
                                            f32x4 acc[4][BNF])
{
    const int t    = threadIdx.x;
    const int lane = t & 63, wid = t >> 6;
    const int wm = wid >> 1, wn = wid & 1;
    const int lrow = lane & 15, kg = lane >> 4;
    const int sr = lane >> 2;                              // row within a 16-row staging slab
    const int sg = ((lane & 3) ^ ((lane >> 3) & 3)) * 8;   // pre-swizzled source granule col

    auto stage = [&](int buf, int ks) {
        #pragma unroll
        for (int i = 0; i < 2; i++) {
            int row = wid * 32 + i * 16;
            load_lds16(&A[(size_t)(m0 + row + sr) * K + ks + sg], &As[buf * 128 + row][0]);
        }
        if constexpr (BNF == 4) {
            #pragma unroll
            for (int i = 0; i < 2; i++) {
                int row = wid * 32 + i * 16;
                load_lds16(&BT[(size_t)(n0 + row + sr) * K + ks + sg], &Bs[buf * 128 + row][0]);
            }
        } else {
            int row = wid * 16;
            load_lds16(&BT[(size_t)(n0 + row + sr) * K + ks + sg], &Bs[buf * 64 + row][0]);
        }
    };

    stage(0, 0);
    __syncthreads();
    int buf = 0;
    for (int ks = 0; ks < K; ks += 32) {
        if (ks + 32 < K) stage(buf ^ 1, ks + 32);
        const int rg = (kg ^ ((lrow >> 1) & 3)) * 8;       // swizzled read granule
        bf16x8 af[4], bfv[BNF];
        #pragma unroll
        for (int i = 0; i < 4; i++)
            af[i] = *(const bf16x8*)&As[buf * 128 + wm * 64 + i * 16 + lrow][rg];
        #pragma unroll
        for (int j = 0; j < BNF; j++)
            bfv[j] = *(const bf16x8*)&Bs[buf * (BNF * 32) + wn * (BNF * 16) + j * 16 + lrow][rg];
        #pragma unroll
        for (int i = 0; i < 4; i++)
            #pragma unroll
            for (int j = 0; j < BNF; j++)
                acc[i][j] = __builtin_amdgcn_mfma_f32_16x16x32_bf16(af[i], bfv[j], acc[i][j], 0, 0, 0);
        __syncthreads();
        buf ^= 1;
    }
}

// ---------------- batched QKV projection GEMM (z: 0-3 Q_l scaled+masked, 4-7 K_l, 8 V_3) ----------------
// Q pre-scale folds SCALE * log2(e): attn computes hw_exp2(s) == exp(s_raw * 0.125).
__global__ __launch_bounds__(256) void qkv_gemm_kernel(const u16* __restrict__ x16,
                                                       const u16* __restrict__ y16,
                                                       const u16* __restrict__ wt,
                                                       u16* __restrict__ qkv,
                                                       const float* __restrict__ bq,
                                                       const float* __restrict__ bk,
                                                       const float* __restrict__ bv,
                                                       const int* __restrict__ x_mask)
{
    __shared__ u16 As[256][32];
    __shared__ u16 Bs[256][32];
    const int z = blockIdx.z;
    const u16* A; const u16* BT; const float* bias;
    if (z < 4)      { A = x16; BT = wt + (size_t)z * 262144;                 bias = bq + z * 512; }
    else if (z < 8) { A = y16; BT = wt + 1048576 + (size_t)(z - 4) * 262144; bias = bk + (z - 4) * 512; }
    else            { A = y16; BT = wt + 2097152;                            bias = bv + 3 * 512; }
    u16* out = qkv + (size_t)z * 2097152;

    const int m0 = blockIdx.y * 128, n0 = blockIdx.x * 128;
    f32x4 acc[4][4];
    #pragma unroll
    for (int i = 0; i < 4; i++)
        #pragma unroll
        for (int j = 0; j < 4; j++) acc[i][j] = f32x4{0.f, 0.f, 0.f, 0.f};
    gemm_core32<4>(A, BT, 512, m0, n0, As, Bs, acc);

    const int lane = threadIdx.x & 63, wid = threadIdx.x >> 6;
    const int wm = wid >> 1, wn = wid & 1;
    const int lrow = lane & 15, kg = lane >> 4;
    #pragma unroll
    for (int i = 0; i < 4; i++)
        #pragma unroll
        for (int j = 0; j < 4; j++)
            #pragma unroll
            for (int r = 0; r < 4; r++) {
                int row = m0 + wm * 64 + i * 16 + kg * 4 + r;
                int col = n0 + wn * 64 + j * 16 + lrow;
                float v = acc[i][j][r] + bias[col];
                // 0.125 * log2(e)
                if (z < 4) v *= 0.180336880f * (x_mask[row] ? 1.f : 0.f);
                out[(size_t)row * 512 + col] = f2bf(v);
            }
}

// ---------------- generic GEMM with epilogue. EPI 1: f32 out + bias + residual; EPI 2: bf16 out + bias + exact GELU ----------------
template<int BNF, int EPI>
__global__ __launch_bounds__(256) void gemm_bt_kernel(const u16* __restrict__ A,
                                                      const u16* __restrict__ BT,
                                                      const float* __restrict__ bias,
                                                      void* __restrict__ outp,
                                                      const float* __restrict__ res,
                                                      int N, int K)
{
    __shared__ u16 As[256][32];
    __shared__ u16 Bs[BNF * 64][32];
    const int m0 = blockIdx.y * 128, n0 = blockIdx.x * (BNF * 32);
    f32x4 acc[4][BNF];
    #pragma unroll
    for (int i = 0; i < 4; i++)
        #pragma unroll
        for (int j = 0; j < BNF; j++) acc[i][j] = f32x4{0.f, 0.f, 0.f, 0.f};
    gemm_core32<BNF>(A, BT, K, m0, n0, As, Bs, acc);

    const int lane = threadIdx.x & 63, wid = threadIdx.x >> 6;
    const int wm = wid >> 1, wn = wid & 1;
    const int lrow = lane & 15, kg = lane >> 4;
    #pragma unroll
    for (int i = 0; i < 4; i++)
        #pragma unroll
        for (int j = 0; j < BNF; j++)
            #pragma unroll
            for (int r = 0; r < 4; r++) {
                int row = m0 + wm * 64 + i * 16 + kg * 4 + r;
                int col = n0 + wn * (BNF * 16) + j * 16 + lrow;
                float v = acc[i][j][r] + bias[col];
                if constexpr (EPI == 1) {
                    ((float*)outp)[(size_t)row * N + col] = v + res[(size_t)row * N + col];
                } else {
                    v = 0.5f * v * (1.f + erff(v * 0.70710678118654752f));
                    ((u16*)outp)[(size_t)row * N + col] = f2bf(v);
                }
            }
}

// ---------------- V transpose per head: v (b,h,m,d) -> vt (b,h,d,m) ----------------
__global__ __launch_bounds__(256) void vtrans_kernel(const u16* __restrict__ v, u16* __restrict__ vt)
{
    const int bh = blockIdx.y, m0 = blockIdx.x * 64;
    const int b = bh >> 3, h = bh & 7;
    const u16* src = v + (size_t)b * 524288 + (size_t)h * 65536;   // (1024 m, 64 d)
    u16* dst = vt + (size_t)bh * 65536;                            // (64 d, 1024 m)
    __shared__ u16 tile[64][72];
    const int t = threadIdx.x;
    #pragma unroll
    for (int i = 0; i < 2; i++) {
        int idx = t + i * 256, r = idx >> 3, q = idx & 7;
        *(uint4*)&tile[r][q * 8] = *(const uint4*)&src[(size_t)(m0 + r) * 64 + q * 8];
    }
    __syncthreads();
    #pragma unroll
    for (int i = 0; i < 2; i++) {
        int idx = t + i * 256, d = idx >> 3, q = idx & 7;
        alignas(16) u16 tmp[8];
        #pragma unroll
        for (int j = 0; j < 8; j++) tmp[j] = tile[q * 8 + j][d];
        *(uint4*)&dst[(size_t)d * 1024 + m0 + q * 8] = *(uint4*)tmp;
    }
}

// ---------------- fused 4-layer residual attention ----------------
// r10 skeleton exactly (passing, 68.5us) with ONE change: __expf -> raw v_exp_f32
// (log2(e) pre-folded into Q scale). No setprio, scalar ymb reads (r10 bytes).
__global__ __launch_bounds__(256, 2) void attn_kernel(const u16* __restrict__ qkv,
                                                      const int* __restrict__ x_mask,
                                                      const int* __restrict__ y_mask,
                                                      const u16* __restrict__ vt,
                                                      u16* __restrict__ obuf)
{
    __shared__ __align__(16) char smem[45056];
    u16 (*Kb)[4][32][64] = reinterpret_cast<u16(*)[4][32][64]>(smem);        // [2][4][32][64] 32KB
    u16 (*Vb)[64][32]    = reinterpret_cast<u16(*)[64][32]>(smem + 32768);   // [2][64][32]    8KB
    float* ymb           = reinterpret_cast<float*>(smem + 40960);           // [1024]         4KB
    u16 (*Osh)[64][72]   = reinterpret_cast<u16(*)[64][72]>(smem);           // overlay 36KB

    const int t = threadIdx.x;
    const int wid = t >> 6, lane = t & 63;
    const int lrow = lane & 15, kg = lane >> 4;

    const int gid  = blockIdx.x;
    const int orig = (gid & 7) * 64 + (gid >> 3);
    const int bh = orig >> 4, qt = orig & 15;
    const int b = bh >> 3, h = bh & 7;
    const int q0 = qt * 64;

    const size_t headoff = (size_t)b * 524288 + (size_t)h * 65536;
    const u16* Q  = qkv + (size_t)wid * 2097152 + headoff;
    const u16* VT = vt + (size_t)bh * 65536;

    for (int i = t; i < 1024; i += 256)
        ymb[i] = y_mask[b * 1024 + i] ? 0.f : -1e9f;

    const int ksrow = wid * 8 + (lane >> 3);
    const int kscol = ((lane & 7) ^ (lane >> 3)) * 8;
    const int vsrow = wid * 16 + (lane >> 2);
    const int vscol = (((lane & 3) ^ ((vsrow & 3) ^ ((vsrow >> 2) & 3))) * 8);
    const int fswz  = (lrow & 3) ^ ((lrow >> 2) & 3);

    auto stage = [&](int buf, int mt) {
        const int m0 = mt * 32;
        #pragma unroll
        for (int it = 0; it < 4; it++) {
            const u16* src = qkv + (size_t)(4 + it) * 2097152 + headoff
                           + (size_t)(m0 + ksrow) * 64 + kscol;
            load_lds16(src, &Kb[buf][it][wid * 8][0]);
        }
        load_lds16(&VT[(size_t)vsrow * 1024 + m0 + vscol], &Vb[buf][wid * 16][0]);
    };

    bf16x8 aq[4][2];
    #pragma unroll
    for (int i = 0; i < 4; i++) {
        aq[i][0] = *(const bf16x8*)&Q[(size_t)(q0 + i * 16 + lrow) * 64 + kg * 8];
        aq[i][1] = *(const bf16x8*)&Q[(size_t)(q0 + i * 16 + lrow) * 64 + 32 + kg * 8];
    }
    float xmf[4];
    #pragma unroll
    for (int i = 0; i < 4; i++) xmf[i] = x_mask[b * 1024 + q0 + i * 16 + lrow] ? 1.f : 0.f;

    const int srcA = (((2 * kg) & 3) << 4) | lrow;
    const int srcB = (((2 * kg + 1) & 3) << 4) | lrow;

    f32x4 oacc[4][4];
    float psum[4] = {0.f, 0.f, 0.f, 0.f};
    #pragma unroll
    for (int i = 0; i < 4; i++)
        #pragma unroll
        for (int d = 0; d < 4; d++) oacc[i][d] = f32x4{0.f, 0.f, 0.f, 0.f};

    stage(0, 0);
    __syncthreads();

    for (int mt = 0; mt < 32; mt++) {
        const int buf = mt & 1;
        const int m0 = mt * 32;
        if (mt < 31) stage(buf ^ 1, mt + 1);

        bf16x8 kb[2][2];
        #pragma unroll
        for (int nf = 0; nf < 2; nf++)
            #pragma unroll
            for (int kk = 0; kk < 2; kk++)
                kb[nf][kk] = *(const bf16x8*)&Kb[buf][wid][nf * 16 + lrow][((kk * 4 + kg) ^ (lrow & 7)) * 8];

        float yb[2][4];
        #pragma unroll
        for (int nf = 0; nf < 2; nf++)
            #pragma unroll
            for (int r = 0; r < 4; r++) yb[nf][r] = ymb[m0 + nf * 16 + kg * 4 + r];

        bf16x8 pa[4];
        #pragma unroll
        for (int i = 0; i < 4; i++) {
            f32x4 s0 = f32x4{0.f, 0.f, 0.f, 0.f}, s1 = f32x4{0.f, 0.f, 0.f, 0.f};
            s0 = __builtin_amdgcn_mfma_f32_16x16x32_bf16(kb[0][0], aq[i][0], s0, 0, 0, 0);
            s0 = __builtin_amdgcn_mfma_f32_16x16x32_bf16(kb[0][1], aq[i][1], s0, 0, 0, 0);
            s1 = __builtin_amdgcn_mfma_f32_16x16x32_bf16(kb[1][0], aq[i][0], s1, 0, 0, 0);
            s1 = __builtin_amdgcn_mfma_f32_16x16x32_bf16(kb[1][1], aq[i][1], s1, 0, 0, 0);
            float p0 = hw_exp2(fmaf(xmf[i], yb[0][0], s0[0]));
            float p1 = hw_exp2(fmaf(xmf[i], yb[0][1], s0[1]));
            float p2 = hw_exp2(fmaf(xmf[i], yb[0][2], s0[2]));
            float p3 = hw_exp2(fmaf(xmf[i], yb[0][3], s0[3]));
            float p4 = hw_exp2(fmaf(xmf[i], yb[1][0], s1[0]));
            float p5 = hw_exp2(fmaf(xmf[i], yb[1][1], s1[1]));
            float p6 = hw_exp2(fmaf(xmf[i], yb[1][2], s1[2]));
            float p7 = hw_exp2(fmaf(xmf[i], yb[1][3], s1[3]));
            psum[i] += ((p0 + p1) + (p2 + p3)) + ((p4 + p5) + (p6 + p7));
            u32 w0 = pk_bf16(p0, p1), w1 = pk_bf16(p2, p3);
            u32 w2 = pk_bf16(p4, p5), w3 = pk_bf16(p6, p7);
            u32 a0 = __shfl(w0, srcA), a1 = __shfl(w1, srcA);
            u32 a2 = __shfl(w0, srcB), a3 = __shfl(w1, srcB);
            u32 b0 = __shfl(w2, srcA), b1 = __shfl(w3, srcA);
            u32 b2 = __shfl(w2, srcB), b3 = __shfl(w3, srcB);
            const bool hi = (kg & 2) != 0;
            uint4 pw;
            pw.x = hi ? b0 : a0;
            pw.y = hi ? b1 : a1;
            pw.z = hi ? b2 : a2;
            pw.w = hi ? b3 : a3;
            pa[i] = __builtin_bit_cast(bf16x8, pw);
        }

        bf16x8 vbf[4];
        #pragma unroll
        for (int d = 0; d < 4; d++)
            vbf[d] = *(const bf16x8*)&Vb[buf][d * 16 + lrow][(kg ^ fswz) * 8];
        #pragma unroll
        for (int i = 0; i < 4; i++)
            #pragma unroll
            for (int d = 0; d < 4; d++)
                oacc[i][d] = __builtin_amdgcn_mfma_f32_16x16x32_bf16(pa[i], vbf[d], oacc[i][d], 0, 0, 0);

        __syncthreads();
    }

    #pragma unroll
    for (int i = 0; i < 4; i++) {
        psum[i] += __shfl_xor(psum[i], 16);
        psum[i] += __shfl_xor(psum[i], 32);
    }
    float invr[4][4];
    #pragma unroll
    for (int i = 0; i < 4; i++) {
        float inv = 1.f / psum[i];
        #pragma unroll
        for (int r = 0; r < 4; r++) invr[i][r] = __shfl(inv, kg * 4 + r, 16);
    }

    #pragma unroll
    for (int i = 0; i < 4; i++)
        #pragma unroll
        for (int d = 0; d < 4; d++)
            #pragma unroll
            for (int r = 0; r < 4; r++)
                Osh[wid][i * 16 + kg * 4 + r][d * 16 + lrow] = f2bf(oacc[i][d][r] * invr[i][r]);
    __syncthreads();

    {
        const int row = t >> 2, cbase = (t & 3) * 16;
        #pragma unroll
        for (int half = 0; half < 2; half++) {
            const int c0 = cbase + half * 8;
            float a8[8] = {0, 0, 0, 0, 0, 0, 0, 0};
            #pragma unroll
            for (int l = 0; l < 4; l++) {
                uint4 v = *(const uint4*)&Osh[l][row][c0];
                const u16* pv = (const u16*)&v;
                #pragma unroll
                for (int j = 0; j < 8; j++) a8[j] += bf2f(pv[j]);
            }
            alignas(16) u16 tmp[8];
            #pragma unroll
            for (int j = 0; j < 8; j++) tmp[j] = f2bf(a8[j]);
            *(uint4*)&obuf[(size_t)(b * 1024 + q0 + row) * 512 + h * 64 + c0] = *(uint4*)tmp;
        }
    }
}

// ---------------- LayerNorm (one wave per row of 512). MODE 0: write f32 + bf16; MODE 1: f32 only ----------------
template<int MODE>
__global__ __launch_bounds__(256) void ln_kernel(const float* __restrict__ in,
                                                 const float* __restrict__ g,
                                                 const float* __restrict__ be,
                                                 float* __restrict__ out32,
                                                 u16* __restrict__ out16)
{
    const int wid = threadIdx.x >> 6, lane = threadIdx.x & 63;
    const int row = blockIdx.x * 4 + wid;
    const float* x = in + (size_t)row * 512;
    float4 v1 = *(const float4*)&x[lane * 8];
    float4 v2 = *(const float4*)&x[lane * 8 + 4];
    float xv[8] = { v1.x, v1.y, v1.z, v1.w, v2.x, v2.y, v2.z, v2.w };
    float s = 0.f, s2 = 0.f;
    #pragma unroll
    for (int j = 0; j < 8; j++) { s += xv[j]; s2 += xv[j] * xv[j]; }
    #pragma unroll
    for (int off = 32; off > 0; off >>= 1) {
        s  += __shfl_xor(s, off, 64);
        s2 += __shfl_xor(s2, off, 64);
    }
    const float mean = s * (1.f / 512.f);
    const float var  = s2 * (1.f / 512.f) - mean * mean;
    const float rstd = rsqrtf(var + 1e-5f);
    float ov[8];
    #pragma unroll
    for (int j = 0; j < 8; j++) {
        int col = lane * 8 + j;
        ov[j] = (xv[j] - mean) * rstd * g[col] + be[col];
    }
    *(float4*)&out32[(size_t)row * 512 + lane * 8]     = float4{ ov[0], ov[1], ov[2], ov[3] };
    *(float4*)&out32[(size_t)row * 512 + lane * 8 + 4] = float4{ ov[4], ov[5], ov[6], ov[7] };
    if constexpr (MODE == 0) {
        alignas(16) u16 tmp[8];
        #pragma unroll
        for (int j = 0; j < 8; j++) tmp[j] = f2bf(ov[j]);
        *(uint4*)&out16[(size_t)row * 512 + lane * 8] = *(uint4*)tmp;
    }
}

extern "C" void kernel_launch(void* const* d_in, const int* in_sizes, int n_in,
                              void* d_out, int out_size, void* d_ws, size_t ws_size,
                              hipStream_t stream) {
    const float* x      = (const float*)d_in[0];
    const float* y      = (const float*)d_in[1];
    const int*   x_mask = (const int*)d_in[2];
    const int*   y_mask = (const int*)d_in[3];
    const float* Wq  = (const float*)d_in[4];
    const float* bq  = (const float*)d_in[5];
    const float* Wk  = (const float*)d_in[6];
    const float* bk  = (const float*)d_in[7];
    const float* Wv  = (const float*)d_in[8];
    const float* bv  = (const float*)d_in[9];
    const float* Wo  = (const float*)d_in[10];
    const float* bo  = (const float*)d_in[11];
    const float* g1  = (const float*)d_in[12];
    const float* be1 = (const float*)d_in[13];
    const float* g2  = (const float*)d_in[14];
    const float* be2 = (const float*)d_in[15];
    const float* W1  = (const float*)d_in[16];
    const float* bf1 = (const float*)d_in[17];
    const float* W2  = (const float*)d_in[18];
    const float* bf2 = (const float*)d_in[19];

    char* p = (char*)d_ws;
    auto alloc = [&](size_t bytes) { char* r = p; p += (bytes + 255) & ~(size_t)255; return r; };
    u16*   x16   = (u16*)alloc(2097152ULL * 2);
    u16*   y16   = (u16*)alloc(2097152ULL * 2);
    u16*   wt    = (u16*)alloc(4718592ULL * 2);
    u16*   qkv   = (u16*)alloc(9ULL * 2097152 * 2);
    u16*   vt    = (u16*)alloc(2097152ULL * 2);
    u16*   obuf  = (u16*)alloc(2097152ULL * 2);
    float* xo    = (float*)alloc(2097152ULL * 4);
    float* h32   = (float*)alloc(2097152ULL * 4);
    u16*   h16   = (u16*)alloc(2097152ULL * 2);
    u16*   ffmid = (u16*)alloc(8388608ULL * 2);
    float* ffout = (float*)alloc(2097152ULL * 4);
    if ((size_t)(p - (char*)d_ws) > ws_size) return;  // ws too small: bail cleanly

    // 1) convert activations to bf16 (fused x+y)
    cvt2_kernel<<<4096, 256, 0, stream>>>(x, y, x16, y16);
    // 2) transpose+convert the 12 needed weight matrices (exact 4608-tile grid)
    wtrans_kernel<<<4608, dim3(32, 8), 0, stream>>>(Wq, Wk, Wv, Wo, W1, W2, wt);
    // 3) Q_l (scaled*log2e, masked), K_l (l=0..3), V_3 projections
    qkv_gemm_kernel<<<dim3(4, 32, 9), 256, 0, stream>>>(x16, y16, wt, qkv, bq, bk, bv, x_mask);
    // 4) per-head V transpose
    vtrans_kernel<<<dim3(16, 32), 256, 0, stream>>>(qkv + 8ULL * 2097152, vt);
    // 5) fused 4-layer residual attention (QB=64, grid 512)
    attn_kernel<<<512, 256, 0, stream>>>(qkv, x_mask, y_mask, vt, obuf);
    // 6) o@Wo + bo + x -> xo (f32)   [BN=64 -> 256 blocks]
    gemm_bt_kernel<2, 1><<<dim3(8, 32), 256, 0, stream>>>(obuf, wt + 2359296, bo + 3 * 512, xo, x, 512, 512);
    // 7) LN1 -> h (f32 + bf16)
    ln_kernel<0><<<1024, 256, 0, stream>>>(xo, g1 + 3 * 512, be1 + 3 * 512, h32, h16);
    // 8) gelu(h@W1 + bf1) -> ffmid (bf16)   [BN=128 -> 512 blocks]
    gemm_bt_kernel<4, 2><<<dim3(16, 32), 256, 0, stream>>>(h16, wt + 2621440, bf1 + 3 * 2048, ffmid, nullptr, 2048, 512);
    // 9) ffmid@W2 + bf2 + h -> ffout (f32)   [BN=64 -> 256 blocks]
    gemm_bt_kernel<2, 1><<<dim3(8, 32), 256, 0, stream>>>(ffmid, wt + 3670016, bf2 + 3 * 512, ffout, h32, 512, 2048);
    // 10) LN2 -> d_out (f32)
    ln_kernel<1><<<1024, 256, 0, stream>>>(ffout, g2 + 3 * 512, be2 + 3 * 512, (float*)d_out, nullptr);
}

// Round 17
// 185.324 us; speedup vs baseline: 1.0029x; 1.0029x over previous
//
#include <hip/hip_runtime.h>
#include <cstdint>

using u16    = unsigned short;
using u32    = unsigned int;
using bf16x8 = __attribute__((ext_vector_type(8))) __bf16;
using f32x4  = __attribute__((ext_vector_type(4))) float;

__device__ __forceinline__ u16 f2bf(float f) {
    u32 u = __builtin_bit_cast(u32, f);
    u += 0x7FFFu + ((u >> 16) & 1u);
    return (u16)(u >> 16);
}
__device__ __forceinline__ float bf2f(u16 u) {
    return __builtin_bit_cast(float, (u32)u << 16);
}
__device__ __forceinline__ u32 pk_bf16(float a, float b) {
    u32 r;
    asm("v_cvt_pk_bf16_f32 %0, %1, %2" : "=v"(r) : "v"(a), "v"(b));
    return r;
}
// raw 2^x (v_exp_f32 IS exp2 in hardware; single TRANS op, no libm path)
__device__ __forceinline__ float hw_exp2(float x) {
    float r;
    asm("v_exp_f32 %0, %1" : "=v"(r) : "v"(x));
    return r;
}
__device__ __forceinline__ void load_lds16(const u16* g, u16* l) {
    __builtin_amdgcn_global_load_lds((const __attribute__((address_space(1))) void*)g,
                                     (__attribute__((address_space(3))) void*)l, 16, 0, 0);
}

// ---------------- fused f32 -> bf16 convert for x and y ----------------
__global__ __launch_bounds__(256) void cvt2_kernel(const float* __restrict__ a,
                                                   const float* __restrict__ b,
                                                   u16* __restrict__ oa,
                                                   u16* __restrict__ ob)
{
    const int bid = blockIdx.x;
    const float* in = bid < 2048 ? a : b;
    u16* out = bid < 2048 ? oa : ob;
    int i = ((bid & 2047) * 256 + threadIdx.x) * 4;
    float4 v = *(const float4*)(in + i);
    uint2 o;
    o.x = (u32)f2bf(v.x) | ((u32)f2bf(v.y) << 16);
    o.y = (u32)f2bf(v.z) | ((u32)f2bf(v.w) << 16);
    *(uint2*)(out + i) = o;
}

// ---------------- weight transpose + convert (flat exact grid: 4608 blocks) ----------------
__global__ __launch_bounds__(256) void wtrans_kernel(const float* __restrict__ Wq,
                                                     const float* __restrict__ Wk,
                                                     const float* __restrict__ Wv,
                                                     const float* __restrict__ Wo,
                                                     const float* __restrict__ W1,
                                                     const float* __restrict__ W2,
                                                     u16* __restrict__ wt)
{
    const int gid = blockIdx.x;
    const float* src; u16* dst; int K = 512, N = 512; int n0, k0;
    if (gid < 2560) {
        int z = gid >> 8, tid = gid & 255;
        switch (z) {
            case 0: case 1: case 2: case 3:
                src = Wq + (size_t)z * 262144;        dst = wt + (size_t)z * 262144;            break;
            case 4: case 5: case 6: case 7:
                src = Wk + (size_t)(z - 4) * 262144;  dst = wt + 1048576 + (size_t)(z - 4) * 262144; break;
            case 8: src = Wv + 3 * 262144;  dst = wt + 2097152; break;
            default: src = Wo + 3 * 262144; dst = wt + 2359296; break;
        }
        n0 = (tid & 15) * 32; k0 = (tid >> 4) * 32;
    } else if (gid < 3584) {
        int tid = gid - 2560;
        src = W1 + 3 * 1048576; dst = wt + 2621440; K = 512; N = 2048;
        n0 = (tid & 63) * 32; k0 = (tid >> 6) * 32;
    } else {
        int tid = gid - 3584;
        src = W2 + 3 * 1048576; dst = wt + 3670016; K = 2048; N = 512;
        n0 = (tid & 15) * 32; k0 = (tid >> 4) * 32;
    }
    __shared__ float tile[32][33];
    int tx = threadIdx.x, ty = threadIdx.y;
    #pragma unroll
    for (int i = 0; i < 4; i++) {
        int r = ty + i * 8;
        tile[r][tx] = src[(size_t)(k0 + r) * N + n0 + tx];
    }
    __syncthreads();
    #pragma unroll
    for (int i = 0; i < 4; i++) {
        int rn = ty + i * 8;
        dst[(size_t)(n0 + rn) * K + k0 + tx] = f2bf(tile[tx][rn]);
    }
}

// ---------------- BK=32 double-buffered GEMM core (m97 shape + 2-phase + XOR swizzle) ----------------
template<int BNF>
__device__ __forceinline__ void gemm_core32(const u16* __restrict__ A,
                                            const u16* __restrict__ BT,
                                            int K, int m0, int n0,
                                            u16 (*As)[32], u16 (*Bs)[32],
                                            f32x4 acc[4][BNF])
{
    const int t    = threadIdx.x;
    const int lane = t & 63, wid = t >> 6;
    const int wm = wid >> 1, wn = wid & 1;
    const int lrow = lane & 15, kg = lane >> 4;
    const int sr = lane >> 2;                              // row within a 16-row staging slab
    const int sg = ((lane & 3) ^ ((lane >> 3) & 3)) * 8;   // pre-swizzled source granule col

    auto stage = [&](int buf, int ks) {
        #pragma unroll
        for (int i = 0; i < 2; i++) {
            int row = wid * 32 + i * 16;
            load_lds16(&A[(size_t)(m0 + row + sr) * K + ks + sg], &As[buf * 128 + row][0]);
        }
        if constexpr (BNF == 4) {
            #pragma unroll
            for (int i = 0; i < 2; i++) {
                int row = wid * 32 + i * 16;
                load_lds16(&BT[(size_t)(n0 + row + sr) * K + ks + sg], &Bs[buf * 128 + row][0]);
            }
        } else {
            int row = wid * 16;
            load_lds16(&BT[(size_t)(n0 + row + sr) * K + ks + sg], &Bs[buf * 64 + row][0]);
        }
    };

    stage(0, 0);
    __syncthreads();
    int buf = 0;
    for (int ks = 0; ks < K; ks += 32) {
        if (ks + 32 < K) stage(buf ^ 1, ks + 32);
        const int rg = (kg ^ ((lrow >> 1) & 3)) * 8;       // swizzled read granule
        bf16x8 af[4], bfv[BNF];
        #pragma unroll
        for (int i = 0; i < 4; i++)
            af[i] = *(const bf16x8*)&As[buf * 128 + wm * 64 + i * 16 + lrow][rg];
        #pragma unroll
        for (int j = 0; j < BNF; j++)
            bfv[j] = *(const bf16x8*)&Bs[buf * (BNF * 32) + wn * (BNF * 16) + j * 16 + lrow][rg];
        #pragma unroll
        for (int i = 0; i < 4; i++)
            #pragma unroll
            for (int j = 0; j < BNF; j++)
                acc[i][j] = __builtin_amdgcn_mfma_f32_16x16x32_bf16(af[i], bfv[j], acc[i][j], 0, 0, 0);
        __syncthreads();
        buf ^= 1;
    }
}

// ---------------- batched QKV projection GEMM (z: 0-3 Q_l scaled+masked, 4-7 K_l, 8 V_3) ----------------
// Q pre-scale folds SCALE * log2(e): attn computes hw_exp2(s) == exp(s_raw * 0.125).
__global__ __launch_bounds__(256) void qkv_gemm_kernel(const u16* __restrict__ x16,
                                                       const u16* __restrict__ y16,
                                                       const u16* __restrict__ wt,
                                                       u16* __restrict__ qkv,
                                                       const float* __restrict__ bq,
                                                       const float* __restrict__ bk,
                                                       const float* __restrict__ bv,
                                                       const int* __restrict__ x_mask)
{
    __shared__ u16 As[256][32];
    __shared__ u16 Bs[256][32];
    const int z = blockIdx.z;
    const u16* A; const u16* BT; const float* bias;
    if (z < 4)      { A = x16; BT = wt + (size_t)z * 262144;                 bias = bq + z * 512; }
    else if (z < 8) { A = y16; BT = wt + 1048576 + (size_t)(z - 4) * 262144; bias = bk + (z - 4) * 512; }
    else            { A = y16; BT = wt + 2097152;                            bias = bv + 3 * 512; }
    u16* out = qkv + (size_t)z * 2097152;

    const int m0 = blockIdx.y * 128, n0 = blockIdx.x * 128;
    f32x4 acc[4][4];
    #pragma unroll
    for (int i = 0; i < 4; i++)
        #pragma unroll
        for (int j = 0; j < 4; j++) acc[i][j] = f32x4{0.f, 0.f, 0.f, 0.f};
    gemm_core32<4>(A, BT, 512, m0, n0, As, Bs, acc);

    const int lane = threadIdx.x & 63, wid = threadIdx.x >> 6;
    const int wm = wid >> 1, wn = wid & 1;
    const int lrow = lane & 15, kg = lane >> 4;
    #pragma unroll
    for (int i = 0; i < 4; i++)
        #pragma unroll
        for (int j = 0; j < 4; j++)
            #pragma unroll
            for (int r = 0; r < 4; r++) {
                int row = m0 + wm * 64 + i * 16 + kg * 4 + r;
                int col = n0 + wn * 64 + j * 16 + lrow;
                float v = acc[i][j][r] + bias[col];
                // 0.125 * log2(e)
                if (z < 4) v *= 0.180336880f * (x_mask[row] ? 1.f : 0.f);
                out[(size_t)row * 512 + col] = f2bf(v);
            }
}

// ---------------- generic GEMM with epilogue. EPI 1: f32 out + bias + residual; EPI 2: bf16 out + bias + exact GELU ----------------
template<int BNF, int EPI>
__global__ __launch_bounds__(256) void gemm_bt_kernel(const u16* __restrict__ A,
                                                      const u16* __restrict__ BT,
                                                      const float* __restrict__ bias,
                                                      void* __restrict__ outp,
                                                      const float* __restrict__ res,
                                                      int N, int K)
{
    __shared__ u16 As[256][32];
    __shared__ u16 Bs[BNF * 64][32];
    const int m0 = blockIdx.y * 128, n0 = blockIdx.x * (BNF * 32);
    f32x4 acc[4][BNF];
    #pragma unroll
    for (int i = 0; i < 4; i++)
        #pragma unroll
        for (int j = 0; j < BNF; j++) acc[i][j] = f32x4{0.f, 0.f, 0.f, 0.f};
    gemm_core32<BNF>(A, BT, K, m0, n0, As, Bs, acc);

    const int lane = threadIdx.x & 63, wid = threadIdx.x >> 6;
    const int wm = wid >> 1, wn = wid & 1;
    const int lrow = lane & 15, kg = lane >> 4;
    #pragma unroll
    for (int i = 0; i < 4; i++)
        #pragma unroll
        for (int j = 0; j < BNF; j++)
            #pragma unroll
            for (int r = 0; r < 4; r++) {
                int row = m0 + wm * 64 + i * 16 + kg * 4 + r;
                int col = n0 + wn * (BNF * 16) + j * 16 + lrow;
                float v = acc[i][j][r] + bias[col];
                if constexpr (EPI == 1) {
                    ((float*)outp)[(size_t)row * N + col] = v + res[(size_t)row * N + col];
                } else {
                    v = 0.5f * v * (1.f + erff(v * 0.70710678118654752f));
                    ((u16*)outp)[(size_t)row * N + col] = f2bf(v);
                }
            }
}

// ---------------- V transpose per head: v (b,h,m,d) -> vt (b,h,d,m) ----------------
__global__ __launch_bounds__(256) void vtrans_kernel(const u16* __restrict__ v, u16* __restrict__ vt)
{
    const int bh = blockIdx.y, m0 = blockIdx.x * 64;
    const int b = bh >> 3, h = bh & 7;
    const u16* src = v + (size_t)b * 524288 + (size_t)h * 65536;   // (1024 m, 64 d)
    u16* dst = vt + (size_t)bh * 65536;                            // (64 d, 1024 m)
    __shared__ u16 tile[64][72];
    const int t = threadIdx.x;
    #pragma unroll
    for (int i = 0; i < 2; i++) {
        int idx = t + i * 256, r = idx >> 3, q = idx & 7;
        *(uint4*)&tile[r][q * 8] = *(const uint4*)&src[(size_t)(m0 + r) * 64 + q * 8];
    }
    __syncthreads();
    #pragma unroll
    for (int i = 0; i < 2; i++) {
        int idx = t + i * 256, d = idx >> 3, q = idx & 7;
        alignas(16) u16 tmp[8];
        #pragma unroll
        for (int j = 0; j < 8; j++) tmp[j] = tile[q * 8 + j][d];
        *(uint4*)&dst[(size_t)d * 1024 + m0 + q * 8] = *(uint4*)tmp;
    }
}

// ---------------- fused 4-layer residual attention, 8-wave blocks ----------------
// Same block<->(bh, qt) mapping and LDS tiles as the passing r10/r16 kernel, but 512
// threads = 8 waves: wave w = (q-half w>>2, layer w&3), 32 q-rows per wave. Doubles
// waves/SIMD (2 -> 4) for latency hiding; per-wave serial chain halves. K staged as
// flattened [4*32] rows, 2 loads/thread, identical XOR swizzle (row&7 == lane>>3).
__global__ __launch_bounds__(512) void attn_kernel(const u16* __restrict__ qkv,
                                                   const int* __restrict__ x_mask,
                                                   const int* __restrict__ y_mask,
                                                   const u16* __restrict__ vt,
                                                   u16* __restrict__ obuf)
{
    __shared__ __align__(16) char smem[45056];
    u16 (*Kb)[4][32][64] = reinterpret_cast<u16(*)[4][32][64]>(smem);        // [2][4][32][64] 32KB
    u16 (*Vb)[64][32]    = reinterpret_cast<u16(*)[64][32]>(smem + 32768);   // [2][64][32]    8KB
    float* ymb           = reinterpret_cast<float*>(smem + 40960);           // [1024]         4KB
    u16 (*Osh)[32][72]   = reinterpret_cast<u16(*)[32][72]>(smem);           // overlay [8][32][72] 36KB

    const int t = threadIdx.x;
    const int wid = t >> 6, lane = t & 63;
    const int lrow = lane & 15, kg = lane >> 4;
    const int L  = wid & 3;        // layer
    const int qh = wid >> 2;       // q-half (0: rows 0-31, 1: rows 32-63)

    const int gid  = blockIdx.x;
    const int orig = (gid & 7) * 64 + (gid >> 3);
    const int bh = orig >> 4, qt = orig & 15;
    const int b = bh >> 3, h = bh & 7;
    const int q0 = qt * 64;

    const size_t headoff = (size_t)b * 524288 + (size_t)h * 65536;
    const u16* Q  = qkv + (size_t)L * 2097152 + headoff;
    const u16* VT = vt + (size_t)bh * 65536;

    for (int i = t; i < 1024; i += 512)
        ymb[i] = y_mask[b * 1024 + i] ? 0.f : -1e9f;

    // K staging: flat rows fr = i*64 + wid*8 + (lane>>3) over [4 layers][32 rows];
    // fr&7 == lane>>3, so the swizzled source col is identical to r10's kscol.
    const int kscol = ((lane & 7) ^ (lane >> 3)) * 8;
    // V staging (waves 0-3 only): identical to r10.
    const int vsrow = wid * 16 + (lane >> 2);
    const int vscol = (((lane & 3) ^ ((vsrow & 3) ^ ((vsrow >> 2) & 3))) * 8);
    const int fswz  = (lrow & 3) ^ ((lrow >> 2) & 3);

    auto stage = [&](int buf, int mt) {
        const int m0 = mt * 32;
        u16* kbase = &Kb[buf][0][0][0];
        #pragma unroll
        for (int i = 0; i < 2; i++) {
            const int fr = i * 64 + wid * 8 + (lane >> 3);
            const int it = fr >> 5, r = fr & 31;
            const u16* src = qkv + (size_t)(4 + it) * 2097152 + headoff
                           + (size_t)(m0 + r) * 64 + kscol;
            load_lds16(src, kbase + (i * 512 + wid * 64) * 8);
        }
        if (wid < 4)
            load_lds16(&VT[(size_t)vsrow * 1024 + m0 + vscol], &Vb[buf][wid * 16][0]);
    };

    bf16x8 aq[2][2];
    #pragma unroll
    for (int i = 0; i < 2; i++) {
        const int qr = q0 + qh * 32 + i * 16 + lrow;
        aq[i][0] = *(const bf16x8*)&Q[(size_t)qr * 64 + kg * 8];
        aq[i][1] = *(const bf16x8*)&Q[(size_t)qr * 64 + 32 + kg * 8];
    }
    float xmf[2];
    #pragma unroll
    for (int i = 0; i < 2; i++)
        xmf[i] = x_mask[b * 1024 + q0 + qh * 32 + i * 16 + lrow] ? 1.f : 0.f;

    const int srcA = (((2 * kg) & 3) << 4) | lrow;
    const int srcB = (((2 * kg + 1) & 3) << 4) | lrow;

    f32x4 oacc[2][4];
    float psum[2] = {0.f, 0.f};
    #pragma unroll
    for (int i = 0; i < 2; i++)
        #pragma unroll
        for (int d = 0; d < 4; d++) oacc[i][d] = f32x4{0.f, 0.f, 0.f, 0.f};

    stage(0, 0);
    __syncthreads();

    for (int mt = 0; mt < 32; mt++) {
        const int buf = mt & 1;
        const int m0 = mt * 32;
        if (mt < 31) stage(buf ^ 1, mt + 1);

        bf16x8 kb[2][2];
        #pragma unroll
        for (int nf = 0; nf < 2; nf++)
            #pragma unroll
            for (int kk = 0; kk < 2; kk++)
                kb[nf][kk] = *(const bf16x8*)&Kb[buf][L][nf * 16 + lrow][((kk * 4 + kg) ^ (lrow & 7)) * 8];

        float yb[2][4];
        #pragma unroll
        for (int nf = 0; nf < 2; nf++)
            #pragma unroll
            for (int r = 0; r < 4; r++) yb[nf][r] = ymb[m0 + nf * 16 + kg * 4 + r];

        bf16x8 pa[2];
        #pragma unroll
        for (int i = 0; i < 2; i++) {
            f32x4 s0 = f32x4{0.f, 0.f, 0.f, 0.f}, s1 = f32x4{0.f, 0.f, 0.f, 0.f};
            s0 = __builtin_amdgcn_mfma_f32_16x16x32_bf16(kb[0][0], aq[i][0], s0, 0, 0, 0);
            s0 = __builtin_amdgcn_mfma_f32_16x16x32_bf16(kb[0][1], aq[i][1], s0, 0, 0, 0);
            s1 = __builtin_amdgcn_mfma_f32_16x16x32_bf16(kb[1][0], aq[i][0], s1, 0, 0, 0);
            s1 = __builtin_amdgcn_mfma_f32_16x16x32_bf16(kb[1][1], aq[i][1], s1, 0, 0, 0);
            float p0 = hw_exp2(fmaf(xmf[i], yb[0][0], s0[0]));
            float p1 = hw_exp2(fmaf(xmf[i], yb[0][1], s0[1]));
            float p2 = hw_exp2(fmaf(xmf[i], yb[0][2], s0[2]));
            float p3 = hw_exp2(fmaf(xmf[i], yb[0][3], s0[3]));
            float p4 = hw_exp2(fmaf(xmf[i], yb[1][0], s1[0]));
            float p5 = hw_exp2(fmaf(xmf[i], yb[1][1], s1[1]));
            float p6 = hw_exp2(fmaf(xmf[i], yb[1][2], s1[2]));
            float p7 = hw_exp2(fmaf(xmf[i], yb[1][3], s1[3]));
            psum[i] += ((p0 + p1) + (p2 + p3)) + ((p4 + p5) + (p6 + p7));
            u32 w0 = pk_bf16(p0, p1), w1 = pk_bf16(p2, p3);
            u32 w2 = pk_bf16(p4, p5), w3 = pk_bf16(p6, p7);
            u32 a0 = __shfl(w0, srcA), a1 = __shfl(w1, srcA);
            u32 a2 = __shfl(w0, srcB), a3 = __shfl(w1, srcB);
            u32 b0 = __shfl(w2, srcA), b1 = __shfl(w3, srcA);
            u32 b2 = __shfl(w2, srcB), b3 = __shfl(w3, srcB);
            const bool hi = (kg & 2) != 0;
            uint4 pw;
            pw.x = hi ? b0 : a0;
            pw.y = hi ? b1 : a1;
            pw.z = hi ? b2 : a2;
            pw.w = hi ? b3 : a3;
            pa[i] = __builtin_bit_cast(bf16x8, pw);
        }

        bf16x8 vbf[4];
        #pragma unroll
        for (int d = 0; d < 4; d++)
            vbf[d] = *(const bf16x8*)&Vb[buf][d * 16 + lrow][(kg ^ fswz) * 8];
        #pragma unroll
        for (int i = 0; i < 2; i++)
            #pragma unroll
            for (int d = 0; d < 4; d++)
                oacc[i][d] = __builtin_amdgcn_mfma_f32_16x16x32_bf16(pa[i], vbf[d], oacc[i][d], 0, 0, 0);

        __syncthreads();
    }

    #pragma unroll
    for (int i = 0; i < 2; i++) {
        psum[i] += __shfl_xor(psum[i], 16);
        psum[i] += __shfl_xor(psum[i], 32);
    }
    float invr[2][4];
    #pragma unroll
    for (int i = 0; i < 2; i++) {
        float inv = 1.f / psum[i];
        #pragma unroll
        for (int r = 0; r < 4; r++) invr[i][r] = __shfl(inv, kg * 4 + r, 16);
    }

    #pragma unroll
    for (int i = 0; i < 2; i++)
        #pragma unroll
        for (int d = 0; d < 4; d++)
            #pragma unroll
            for (int r = 0; r < 4; r++)
                Osh[wid][i * 16 + kg * 4 + r][d * 16 + lrow] = f2bf(oacc[i][d][r] * invr[i][r]);
    __syncthreads();

    // combine 4 layers: row64 = t>>3 (0..63), c0 = (t&7)*8; source wave = (row64>>5)*4 + l
    {
        const int row64 = t >> 3, c0 = (t & 7) * 8;
        const int wbase = (row64 >> 5) * 4, lr = row64 & 31;
        float a8[8] = {0, 0, 0, 0, 0, 0, 0, 0};
        #pragma unroll
        for (int l = 0; l < 4; l++) {
            uint4 v = *(const uint4*)&Osh[wbase + l][lr][c0];
            const u16* pv = (const u16*)&v;
            #pragma unroll
            for (int j = 0; j < 8; j++) a8[j] += bf2f(pv[j]);
        }
        alignas(16) u16 tmp[8];
        #pragma unroll
        for (int j = 0; j < 8; j++) tmp[j] = f2bf(a8[j]);
        *(uint4*)&obuf[(size_t)(b * 1024 + q0 + row64) * 512 + h * 64 + c0] = *(uint4*)tmp;
    }
}

// ---------------- LayerNorm (one wave per row of 512). MODE 0: write f32 + bf16; MODE 1: f32 only ----------------
template<int MODE>
__global__ __launch_bounds__(256) void ln_kernel(const float* __restrict__ in,
                                                 const float* __restrict__ g,
                                                 const float* __restrict__ be,
                                                 float* __restrict__ out32,
                                                 u16* __restrict__ out16)
{
    const int wid = threadIdx.x >> 6, lane = threadIdx.x & 63;
    const int row = blockIdx.x * 4 + wid;
    const float* x = in + (size_t)row * 512;
    float4 v1 = *(const float4*)&x[lane * 8];
    float4 v2 = *(const float4*)&x[lane * 8 + 4];
    float xv[8] = { v1.x, v1.y, v1.z, v1.w, v2.x, v2.y, v2.z, v2.w };
    float s = 0.f, s2 = 0.f;
    #pragma unroll
    for (int j = 0; j < 8; j++) { s += xv[j]; s2 += xv[j] * xv[j]; }
    #pragma unroll
    for (int off = 32; off > 0; off >>= 1) {
        s  += __shfl_xor(s, off, 64);
        s2 += __shfl_xor(s2, off, 64);
    }
    const float mean = s * (1.f / 512.f);
    const float var  = s2 * (1.f / 512.f) - mean * mean;
    const float rstd = rsqrtf(var + 1e-5f);
    float ov[8];
    #pragma unroll
    for (int j = 0; j < 8; j++) {
        int col = lane * 8 + j;
        ov[j] = (xv[j] - mean) * rstd * g[col] + be[col];
    }
    *(float4*)&out32[(size_t)row * 512 + lane * 8]     = float4{ ov[0], ov[1], ov[2], ov[3] };
    *(float4*)&out32[(size_t)row * 512 + lane * 8 + 4] = float4{ ov[4], ov[5], ov[6], ov[7] };
    if constexpr (MODE == 0) {
        alignas(16) u16 tmp[8];
        #pragma unroll
        for (int j = 0; j < 8; j++) tmp[j] = f2bf(ov[j]);
        *(uint4*)&out16[(size_t)row * 512 + lane * 8] = *(uint4*)tmp;
    }
}

extern "C" void kernel_launch(void* const* d_in, const int* in_sizes, int n_in,
                              void* d_out, int out_size, void* d_ws, size_t ws_size,
                              hipStream_t stream) {
    const float* x      = (const float*)d_in[0];
    const float* y      = (const float*)d_in[1];
    const int*   x_mask = (const int*)d_in[2];
    const int*   y_mask = (const int*)d_in[3];
    const float* Wq  = (const float*)d_in[4];
    const float* bq  = (const float*)d_in[5];
    const float* Wk  = (const float*)d_in[6];
    const float* bk  = (const float*)d_in[7];
    const float* Wv  = (const float*)d_in[8];
    const float* bv  = (const float*)d_in[9];
    const float* Wo  = (const float*)d_in[10];
    const float* bo  = (const float*)d_in[11];
    const float* g1  = (const float*)d_in[12];
    const float* be1 = (const float*)d_in[13];
    const float* g2  = (const float*)d_in[14];
    const float* be2 = (const float*)d_in[15];
    const float* W1  = (const float*)d_in[16];
    const float* bf1 = (const float*)d_in[17];
    const float* W2  = (const float*)d_in[18];
    const float* bf2 = (const float*)d_in[19];

    char* p = (char*)d_ws;
    auto alloc = [&](size_t bytes) { char* r = p; p += (bytes + 255) & ~(size_t)255; return r; };
    u16*   x16   = (u16*)alloc(2097152ULL * 2);
    u16*   y16   = (u16*)alloc(2097152ULL * 2);
    u16*   wt    = (u16*)alloc(4718592ULL * 2);
    u16*   qkv   = (u16*)alloc(9ULL * 2097152 * 2);
    u16*   vt    = (u16*)alloc(2097152ULL * 2);
    u16*   obuf  = (u16*)alloc(2097152ULL * 2);
    float* xo    = (float*)alloc(2097152ULL * 4);
    float* h32   = (float*)alloc(2097152ULL * 4);
    u16*   h16   = (u16*)alloc(2097152ULL * 2);
    u16*   ffmid = (u16*)alloc(8388608ULL * 2);
    float* ffout = (float*)alloc(2097152ULL * 4);
    if ((size_t)(p - (char*)d_ws) > ws_size) return;  // ws too small: bail cleanly

    // 1) convert activations to bf16 (fused x+y)
    cvt2_kernel<<<4096, 256, 0, stream>>>(x, y, x16, y16);
    // 2) transpose+convert the 12 needed weight matrices (exact 4608-tile grid)
    wtrans_kernel<<<4608, dim3(32, 8), 0, stream>>>(Wq, Wk, Wv, Wo, W1, W2, wt);
    // 3) Q_l (scaled*log2e, masked), K_l (l=0..3), V_3 projections
    qkv_gemm_kernel<<<dim3(4, 32, 9), 256, 0, stream>>>(x16, y16, wt, qkv, bq, bk, bv, x_mask);
    // 4) per-head V transpose
    vtrans_kernel<<<dim3(16, 32), 256, 0, stream>>>(qkv + 8ULL * 2097152, vt);
    // 5) fused 4-layer residual attention (QB=64, grid 512, 8-wave blocks)
    attn_kernel<<<512, 512, 0, stream>>>(qkv, x_mask, y_mask, vt, obuf);
    // 6) o@Wo + bo + x -> xo (f32)   [BN=64 -> 256 blocks]
    gemm_bt_kernel<2, 1><<<dim3(8, 32), 256, 0, stream>>>(obuf, wt + 2359296, bo + 3 * 512, xo, x, 512, 512);
    // 7) LN1 -> h (f32 + bf16)
    ln_kernel<0><<<1024, 256, 0, stream>>>(xo, g1 + 3 * 512, be1 + 3 * 512, h32, h16);
    // 8) gelu(h@W1 + bf1) -> ffmid (bf16)   [BN=128 -> 512 blocks]
    gemm_bt_kernel<4, 2><<<dim3(16, 32), 256, 0, stream>>>(h16, wt + 2621440, bf1 + 3 * 2048, ffmid, nullptr, 2048, 512);
    // 9) ffmid@W2 + bf2 + h -> ffout (f32)   [BN=64 -> 256 blocks]
    gemm_bt_kernel<2, 1><<<dim3(8, 32), 256, 0, stream>>>(ffmid, wt + 3670016, bf2 + 3 * 512, ffout, h32, 512, 2048);
    // 10) LN2 -> d_out (f32)
    ln_kernel<1><<<1024, 256, 0, stream>>>(ffout, g2 + 3 * 512, be2 + 3 * 512, (float*)d_out, nullptr);
}

// Round 18
// 176.738 us; speedup vs baseline: 1.0516x; 1.0486x over previous
//
#include <hip/hip_runtime.h>
#include <cstdint>

using u16    = unsigned short;
using u32    = unsigned int;
using bf16x8 = __attribute__((ext_vector_type(8))) __bf16;
using f32x4  = __attribute__((ext_vector_type(4))) float;

__device__ __forceinline__ u16 f2bf(float f) {
    u32 u = __builtin_bit_cast(u32, f);
    u += 0x7FFFu + ((u >> 16) & 1u);
    return (u16)(u >> 16);
}
__device__ __forceinline__ float bf2f(u16 u) {
    return __builtin_bit_cast(float, (u32)u << 16);
}
__device__ __forceinline__ u32 pk_bf16(float a, float b) {
    u32 r;
    asm("v_cvt_pk_bf16_f32 %0, %1, %2" : "=v"(r) : "v"(a), "v"(b));
    return r;
}
// raw 2^x (v_exp_f32 IS exp2 in hardware; single TRANS op, no libm path)
__device__ __forceinline__ float hw_exp2(float x) {
    float r;
    asm("v_exp_f32 %0, %1" : "=v"(r) : "v"(x));
    return r;
}
__device__ __forceinline__ void load_lds16(const u16* g, u16* l) {
    __builtin_amdgcn_global_load_lds((const __attribute__((address_space(1))) void*)g,
                                     (__attribute__((address_space(3))) void*)l, 16, 0, 0);
}

// ---------------- fused f32 -> bf16 convert for x and y ----------------
__global__ __launch_bounds__(256) void cvt2_kernel(const float* __restrict__ a,
                                                   const float* __restrict__ b,
                                                   u16* __restrict__ oa,
                                                   u16* __restrict__ ob)
{
    const int bid = blockIdx.x;
    const float* in = bid < 2048 ? a : b;
    u16* out = bid < 2048 ? oa : ob;
    int i = ((bid & 2047) * 256 + threadIdx.x) * 4;
    float4 v = *(const float4*)(in + i);
    uint2 o;
    o.x = (u32)f2bf(v.x) | ((u32)f2bf(v.y) << 16);
    o.y = (u32)f2bf(v.z) | ((u32)f2bf(v.w) << 16);
    *(uint2*)(out + i) = o;
}

// ---------------- weight transpose + convert (flat exact grid: 4608 blocks) ----------------
__global__ __launch_bounds__(256) void wtrans_kernel(const float* __restrict__ Wq,
                                                     const float* __restrict__ Wk,
                                                     const float* __restrict__ Wv,
                                                     const float* __restrict__ Wo,
                                                     const float* __restrict__ W1,
                                                     const float* __restrict__ W2,
                                                     u16* __restrict__ wt)
{
    const int gid = blockIdx.x;
    const float* src; u16* dst; int K = 512, N = 512; int n0, k0;
    if (gid < 2560) {
        int z = gid >> 8, tid = gid & 255;
        switch (z) {
            case 0: case 1: case 2: case 3:
                src = Wq + (size_t)z * 262144;        dst = wt + (size_t)z * 262144;            break;
            case 4: case 5: case 6: case 7:
                src = Wk + (size_t)(z - 4) * 262144;  dst = wt + 1048576 + (size_t)(z - 4) * 262144; break;
            case 8: src = Wv + 3 * 262144;  dst = wt + 2097152; break;
            default: src = Wo + 3 * 262144; dst = wt + 2359296; break;
        }
        n0 = (tid & 15) * 32; k0 = (tid >> 4) * 32;
    } else if (gid < 3584) {
        int tid = gid - 2560;
        src = W1 + 3 * 1048576; dst = wt + 2621440; K = 512; N = 2048;
        n0 = (tid & 63) * 32; k0 = (tid >> 6) * 32;
    } else {
        int tid = gid - 3584;
        src = W2 + 3 * 1048576; dst = wt + 3670016; K = 2048; N = 512;
        n0 = (tid & 15) * 32; k0 = (tid >> 4) * 32;
    }
    __shared__ float tile[32][33];
    int tx = threadIdx.x, ty = threadIdx.y;
    #pragma unroll
    for (int i = 0; i < 4; i++) {
        int r = ty + i * 8;
        tile[r][tx] = src[(size_t)(k0 + r) * N + n0 + tx];
    }
    __syncthreads();
    #pragma unroll
    for (int i = 0; i < 4; i++) {
        int rn = ty + i * 8;
        dst[(size_t)(n0 + rn) * K + k0 + tx] = f2bf(tile[tx][rn]);
    }
}

// ---------------- BK=32 double-buffered GEMM core (m97 shape + 2-phase + XOR swizzle) ----------------
template<int BNF>
__device__ __forceinline__ void gemm_core32(const u16* __restrict__ A,
                                            const u16* __restrict__ BT,
                                            int K, int m0, int n0,
                                            u16 (*As)[32], u16 (*Bs)[32],
                                            f32x4 acc[4][BNF])
{
    const int t    = threadIdx.x;
    const int lane = t & 63, wid = t >> 6;
    const int wm = wid >> 1, wn = wid & 1;
    const int lrow = lane & 15, kg = lane >> 4;
    const int sr = lane >> 2;                              // row within a 16-row staging slab
    const int sg = ((lane & 3) ^ ((lane >> 3) & 3)) * 8;   // pre-swizzled source granule col

    auto stage = [&](int buf, int ks) {
        #pragma unroll
        for (int i = 0; i < 2; i++) {
            int row = wid * 32 + i * 16;
            load_lds16(&A[(size_t)(m0 + row + sr) * K + ks + sg], &As[buf * 128 + row][0]);
        }
        if constexpr (BNF == 4) {
            #pragma unroll
            for (int i = 0; i < 2; i++) {
                int row = wid * 32 + i * 16;
                load_lds16(&BT[(size_t)(n0 + row + sr) * K + ks + sg], &Bs[buf * 128 + row][0]);
            }
        } else {
            int row = wid * 16;
            load_lds16(&BT[(size_t)(n0 + row + sr) * K + ks + sg], &Bs[buf * 64 + row][0]);
        }
    };

    stage(0, 0);
    __syncthreads();
    int buf = 0;
    for (int ks = 0; ks < K; ks += 32) {
        if (ks + 32 < K) stage(buf ^ 1, ks + 32);
        const int rg = (kg ^ ((lrow >> 1) & 3)) * 8;       // swizzled read granule
        bf16x8 af[4], bfv[BNF];
        #pragma unroll
        for (int i = 0; i < 4; i++)
            af[i] = *(const bf16x8*)&As[buf * 128 + wm * 64 + i * 16 + lrow][rg];
        #pragma unroll
        for (int j = 0; j < BNF; j++)
            bfv[j] = *(const bf16x8*)&Bs[buf * (BNF * 32) + wn * (BNF * 16) + j * 16 + lrow][rg];
        #pragma unroll
        for (int i = 0; i < 4; i++)
            #pragma unroll
            for (int j = 0; j < BNF; j++)
                acc[i][j] = __builtin_amdgcn_mfma_f32_16x16x32_bf16(af[i], bfv[j], acc[i][j], 0, 0, 0);
        __syncthreads();
        buf ^= 1;
    }
}

// ---------------- batched QKV projection GEMM (z: 0-3 Q_l scaled+masked, 4-7 K_l, 8 V_3) ----------------
// Q pre-scale folds SCALE * log2(e): attn computes hw_exp2(s) == exp(s_raw * 0.125).
__global__ __launch_bounds__(256) void qkv_gemm_kernel(const u16* __restrict__ x16,
                                                       const u16* __restrict__ y16,
                                                       const u16* __restrict__ wt,
                                                       u16* __restrict__ qkv,
                                                       const float* __restrict__ bq,
                                                       const float* __restrict__ bk,
                                                       const float* __restrict__ bv,
                                                       const int* __restrict__ x_mask)
{
    __shared__ u16 As[256][32];
    __shared__ u16 Bs[256][32];
    const int z = blockIdx.z;
    const u16* A; const u16* BT; const float* bias;
    if (z < 4)      { A = x16; BT = wt + (size_t)z * 262144;                 bias = bq + z * 512; }
    else if (z < 8) { A = y16; BT = wt + 1048576 + (size_t)(z - 4) * 262144; bias = bk + (z - 4) * 512; }
    else            { A = y16; BT = wt + 2097152;                            bias = bv + 3 * 512; }
    u16* out = qkv + (size_t)z * 2097152;

    const int m0 = blockIdx.y * 128, n0 = blockIdx.x * 128;
    f32x4 acc[4][4];
    #pragma unroll
    for (int i = 0; i < 4; i++)
        #pragma unroll
        for (int j = 0; j < 4; j++) acc[i][j] = f32x4{0.f, 0.f, 0.f, 0.f};
    gemm_core32<4>(A, BT, 512, m0, n0, As, Bs, acc);

    const int lane = threadIdx.x & 63, wid = threadIdx.x >> 6;
    const int wm = wid >> 1, wn = wid & 1;
    const int lrow = lane & 15, kg = lane >> 4;
    #pragma unroll
    for (int i = 0; i < 4; i++)
        #pragma unroll
        for (int j = 0; j < 4; j++)
            #pragma unroll
            for (int r = 0; r < 4; r++) {
                int row = m0 + wm * 64 + i * 16 + kg * 4 + r;
                int col = n0 + wn * 64 + j * 16 + lrow;
                float v = acc[i][j][r] + bias[col];
                // 0.125 * log2(e)
                if (z < 4) v *= 0.180336880f * (x_mask[row] ? 1.f : 0.f);
                out[(size_t)row * 512 + col] = f2bf(v);
            }
}

// ---------------- generic GEMM with epilogue. EPI 1: f32 out + bias + residual; EPI 2: bf16 out + bias + exact GELU ----------------
template<int BNF, int EPI>
__global__ __launch_bounds__(256) void gemm_bt_kernel(const u16* __restrict__ A,
                                                      const u16* __restrict__ BT,
                                                      const float* __restrict__ bias,
                                                      void* __restrict__ outp,
                                                      const float* __restrict__ res,
                                                      int N, int K)
{
    __shared__ u16 As[256][32];
    __shared__ u16 Bs[BNF * 64][32];
    const int m0 = blockIdx.y * 128, n0 = blockIdx.x * (BNF * 32);
    f32x4 acc[4][BNF];
    #pragma unroll
    for (int i = 0; i < 4; i++)
        #pragma unroll
        for (int j = 0; j < BNF; j++) acc[i][j] = f32x4{0.f, 0.f, 0.f, 0.f};
    gemm_core32<BNF>(A, BT, K, m0, n0, As, Bs, acc);

    const int lane = threadIdx.x & 63, wid = threadIdx.x >> 6;
    const int wm = wid >> 1, wn = wid & 1;
    const int lrow = lane & 15, kg = lane >> 4;
    #pragma unroll
    for (int i = 0; i < 4; i++)
        #pragma unroll
        for (int j = 0; j < BNF; j++)
            #pragma unroll
            for (int r = 0; r < 4; r++) {
                int row = m0 + wm * 64 + i * 16 + kg * 4 + r;
                int col = n0 + wn * (BNF * 16) + j * 16 + lrow;
                float v = acc[i][j][r] + bias[col];
                if constexpr (EPI == 1) {
                    ((float*)outp)[(size_t)row * N + col] = v + res[(size_t)row * N + col];
                } else {
                    v = 0.5f * v * (1.f + erff(v * 0.70710678118654752f));
                    ((u16*)outp)[(size_t)row * N + col] = f2bf(v);
                }
            }
}

// ---------------- V transpose per head: v (b,h,m,d) -> vt (b,h,d,m) ----------------
__global__ __launch_bounds__(256) void vtrans_kernel(const u16* __restrict__ v, u16* __restrict__ vt)
{
    const int bh = blockIdx.y, m0 = blockIdx.x * 64;
    const int b = bh >> 3, h = bh & 7;
    const u16* src = v + (size_t)b * 524288 + (size_t)h * 65536;   // (1024 m, 64 d)
    u16* dst = vt + (size_t)bh * 65536;                            // (64 d, 1024 m)
    __shared__ u16 tile[64][72];
    const int t = threadIdx.x;
    #pragma unroll
    for (int i = 0; i < 2; i++) {
        int idx = t + i * 256, r = idx >> 3, q = idx & 7;
        *(uint4*)&tile[r][q * 8] = *(const uint4*)&src[(size_t)(m0 + r) * 64 + q * 8];
    }
    __syncthreads();
    #pragma unroll
    for (int i = 0; i < 2; i++) {
        int idx = t + i * 256, d = idx >> 3, q = idx & 7;
        alignas(16) u16 tmp[8];
        #pragma unroll
        for (int j = 0; j < 8; j++) tmp[j] = tile[q * 8 + j][d];
        *(uint4*)&dst[(size_t)d * 1024 + m0 + q * 8] = *(uint4*)tmp;
    }
}

// ---------------- fused 4-layer residual attention, 8-wave blocks ----------------
// r17 8-wave skeleton (passing, 66.3us) with ONE change: the P repack goes through
// per-wave Ps LDS (r12-verified layout) instead of 16 ds_bpermute + cndmask chains.
// Controlled pairs: Ps beat shfl by ~4-5us at both expf (r4 64.8 vs r10 68.9) and
// libm-exp2f (r12 79.6 vs r14 85). LDS 64KB exactly; 2 blocks/CU at grid 512.
__global__ __launch_bounds__(512) void attn_kernel(const u16* __restrict__ qkv,
                                                   const int* __restrict__ x_mask,
                                                   const int* __restrict__ y_mask,
                                                   const u16* __restrict__ vt,
                                                   u16* __restrict__ obuf)
{
    __shared__ __align__(16) char smem[65536];
    u16 (*Kb)[4][32][64] = reinterpret_cast<u16(*)[4][32][64]>(smem);        // [2][4][32][64] 32KB
    u16 (*Vb)[64][32]    = reinterpret_cast<u16(*)[64][32]>(smem + 32768);   // [2][64][32]    8KB
    float* ymb           = reinterpret_cast<float*>(smem + 40960);           // [1024]         4KB
    u16 (*Ps)[32][40]    = reinterpret_cast<u16(*)[32][40]>(smem + 45056);   // [8][32][40]    20KB
    u16 (*Osh)[32][72]   = reinterpret_cast<u16(*)[32][72]>(smem);           // overlay [8][32][72] 36KB

    const int t = threadIdx.x;
    const int wid = t >> 6, lane = t & 63;
    const int lrow = lane & 15, kg = lane >> 4;
    const int L  = wid & 3;        // layer
    const int qh = wid >> 2;       // q-half (0: rows 0-31, 1: rows 32-63)

    const int gid  = blockIdx.x;
    const int orig = (gid & 7) * 64 + (gid >> 3);
    const int bh = orig >> 4, qt = orig & 15;
    const int b = bh >> 3, h = bh & 7;
    const int q0 = qt * 64;

    const size_t headoff = (size_t)b * 524288 + (size_t)h * 65536;
    const u16* Q  = qkv + (size_t)L * 2097152 + headoff;
    const u16* VT = vt + (size_t)bh * 65536;

    for (int i = t; i < 1024; i += 512)
        ymb[i] = y_mask[b * 1024 + i] ? 0.f : -1e9f;

    // K staging: flat rows fr = i*64 + wid*8 + (lane>>3) over [4 layers][32 rows];
    // fr&7 == lane>>3, so the swizzled source col is identical to r10's kscol.
    const int kscol = ((lane & 7) ^ (lane >> 3)) * 8;
    // V staging (waves 0-3 only): identical to r10.
    const int vsrow = wid * 16 + (lane >> 2);
    const int vscol = (((lane & 3) ^ ((vsrow & 3) ^ ((vsrow >> 2) & 3))) * 8);
    const int fswz  = (lrow & 3) ^ ((lrow >> 2) & 3);

    auto stage = [&](int buf, int mt) {
        const int m0 = mt * 32;
        u16* kbase = &Kb[buf][0][0][0];
        #pragma unroll
        for (int i = 0; i < 2; i++) {
            const int fr = i * 64 + wid * 8 + (lane >> 3);
            const int it = fr >> 5, r = fr & 31;
            const u16* src = qkv + (size_t)(4 + it) * 2097152 + headoff
                           + (size_t)(m0 + r) * 64 + kscol;
            load_lds16(src, kbase + (i * 512 + wid * 64) * 8);
        }
        if (wid < 4)
            load_lds16(&VT[(size_t)vsrow * 1024 + m0 + vscol], &Vb[buf][wid * 16][0]);
    };

    bf16x8 aq[2][2];
    #pragma unroll
    for (int i = 0; i < 2; i++) {
        const int qr = q0 + qh * 32 + i * 16 + lrow;
        aq[i][0] = *(const bf16x8*)&Q[(size_t)qr * 64 + kg * 8];
        aq[i][1] = *(const bf16x8*)&Q[(size_t)qr * 64 + 32 + kg * 8];
    }
    float xmf[2];
    #pragma unroll
    for (int i = 0; i < 2; i++)
        xmf[i] = x_mask[b * 1024 + q0 + qh * 32 + i * 16 + lrow] ? 1.f : 0.f;

    f32x4 oacc[2][4];
    float psum[2] = {0.f, 0.f};
    #pragma unroll
    for (int i = 0; i < 2; i++)
        #pragma unroll
        for (int d = 0; d < 4; d++) oacc[i][d] = f32x4{0.f, 0.f, 0.f, 0.f};

    stage(0, 0);
    __syncthreads();

    for (int mt = 0; mt < 32; mt++) {
        const int buf = mt & 1;
        const int m0 = mt * 32;
        if (mt < 31) stage(buf ^ 1, mt + 1);

        bf16x8 kb[2][2];
        #pragma unroll
        for (int nf = 0; nf < 2; nf++)
            #pragma unroll
            for (int kk = 0; kk < 2; kk++)
                kb[nf][kk] = *(const bf16x8*)&Kb[buf][L][nf * 16 + lrow][((kk * 4 + kg) ^ (lrow & 7)) * 8];

        float yb[2][4];
        #pragma unroll
        for (int nf = 0; nf < 2; nf++)
            #pragma unroll
            for (int r = 0; r < 4; r++) yb[nf][r] = ymb[m0 + nf * 16 + kg * 4 + r];

        // swapped QK^T -> hw exp2 -> pack P via per-wave Ps LDS (rows = q, cols = key)
        #pragma unroll
        for (int i = 0; i < 2; i++) {
            f32x4 s0 = f32x4{0.f, 0.f, 0.f, 0.f}, s1 = f32x4{0.f, 0.f, 0.f, 0.f};
            s0 = __builtin_amdgcn_mfma_f32_16x16x32_bf16(kb[0][0], aq[i][0], s0, 0, 0, 0);
            s0 = __builtin_amdgcn_mfma_f32_16x16x32_bf16(kb[0][1], aq[i][1], s0, 0, 0, 0);
            s1 = __builtin_amdgcn_mfma_f32_16x16x32_bf16(kb[1][0], aq[i][0], s1, 0, 0, 0);
            s1 = __builtin_amdgcn_mfma_f32_16x16x32_bf16(kb[1][1], aq[i][1], s1, 0, 0, 0);
            float p0 = hw_exp2(fmaf(xmf[i], yb[0][0], s0[0]));
            float p1 = hw_exp2(fmaf(xmf[i], yb[0][1], s0[1]));
            float p2 = hw_exp2(fmaf(xmf[i], yb[0][2], s0[2]));
            float p3 = hw_exp2(fmaf(xmf[i], yb[0][3], s0[3]));
            float p4 = hw_exp2(fmaf(xmf[i], yb[1][0], s1[0]));
            float p5 = hw_exp2(fmaf(xmf[i], yb[1][1], s1[1]));
            float p6 = hw_exp2(fmaf(xmf[i], yb[1][2], s1[2]));
            float p7 = hw_exp2(fmaf(xmf[i], yb[1][3], s1[3]));
            psum[i] += ((p0 + p1) + (p2 + p3)) + ((p4 + p5) + (p6 + p7));
            *(u32*)&Ps[wid][i * 16 + lrow][kg * 4]          = pk_bf16(p0, p1);
            *(u32*)&Ps[wid][i * 16 + lrow][kg * 4 + 2]      = pk_bf16(p2, p3);
            *(u32*)&Ps[wid][i * 16 + lrow][16 + kg * 4]     = pk_bf16(p4, p5);
            *(u32*)&Ps[wid][i * 16 + lrow][16 + kg * 4 + 2] = pk_bf16(p6, p7);
        }

        // PV: A-frags from Ps, B-frags from swizzled V tile
        bf16x8 pa[2], vbf[4];
        #pragma unroll
        for (int i = 0; i < 2; i++)
            pa[i] = *(const bf16x8*)&Ps[wid][i * 16 + lrow][kg * 8];
        #pragma unroll
        for (int d = 0; d < 4; d++)
            vbf[d] = *(const bf16x8*)&Vb[buf][d * 16 + lrow][(kg ^ fswz) * 8];
        #pragma unroll
        for (int i = 0; i < 2; i++)
            #pragma unroll
            for (int d = 0; d < 4; d++)
                oacc[i][d] = __builtin_amdgcn_mfma_f32_16x16x32_bf16(pa[i], vbf[d], oacc[i][d], 0, 0, 0);

        __syncthreads();
    }

    #pragma unroll
    for (int i = 0; i < 2; i++) {
        psum[i] += __shfl_xor(psum[i], 16);
        psum[i] += __shfl_xor(psum[i], 32);
    }
    float invr[2][4];
    #pragma unroll
    for (int i = 0; i < 2; i++) {
        float inv = 1.f / psum[i];
        #pragma unroll
        for (int r = 0; r < 4; r++) invr[i][r] = __shfl(inv, kg * 4 + r, 16);
    }

    #pragma unroll
    for (int i = 0; i < 2; i++)
        #pragma unroll
        for (int d = 0; d < 4; d++)
            #pragma unroll
            for (int r = 0; r < 4; r++)
                Osh[wid][i * 16 + kg * 4 + r][d * 16 + lrow] = f2bf(oacc[i][d][r] * invr[i][r]);
    __syncthreads();

    // combine 4 layers: row64 = t>>3 (0..63), c0 = (t&7)*8; source wave = (row64>>5)*4 + l
    {
        const int row64 = t >> 3, c0 = (t & 7) * 8;
        const int wbase = (row64 >> 5) * 4, lr = row64 & 31;
        float a8[8] = {0, 0, 0, 0, 0, 0, 0, 0};
        #pragma unroll
        for (int l = 0; l < 4; l++) {
            uint4 v = *(const uint4*)&Osh[wbase + l][lr][c0];
            const u16* pv = (const u16*)&v;
            #pragma unroll
            for (int j = 0; j < 8; j++) a8[j] += bf2f(pv[j]);
        }
        alignas(16) u16 tmp[8];
        #pragma unroll
        for (int j = 0; j < 8; j++) tmp[j] = f2bf(a8[j]);
        *(uint4*)&obuf[(size_t)(b * 1024 + q0 + row64) * 512 + h * 64 + c0] = *(uint4*)tmp;
    }
}

// ---------------- LayerNorm (one wave per row of 512). MODE 0: write f32 + bf16; MODE 1: f32 only ----------------
template<int MODE>
__global__ __launch_bounds__(256) void ln_kernel(const float* __restrict__ in,
                                                 const float* __restrict__ g,
                                                 const float* __restrict__ be,
                                                 float* __restrict__ out32,
                                                 u16* __restrict__ out16)
{
    const int wid = threadIdx.x >> 6, lane = threadIdx.x & 63;
    const int row = blockIdx.x * 4 + wid;
    const float* x = in + (size_t)row * 512;
    float4 v1 = *(const float4*)&x[lane * 8];
    float4 v2 = *(const float4*)&x[lane * 8 + 4];
    float xv[8] = { v1.x, v1.y, v1.z, v1.w, v2.x, v2.y, v2.z, v2.w };
    float s = 0.f, s2 = 0.f;
    #pragma unroll
    for (int j = 0; j < 8; j++) { s += xv[j]; s2 += xv[j] * xv[j]; }
    #pragma unroll
    for (int off = 32; off > 0; off >>= 1) {
        s  += __shfl_xor(s, off, 64);
        s2 += __shfl_xor(s2, off, 64);
    }
    const float mean = s * (1.f / 512.f);
    const float var  = s2 * (1.f / 512.f) - mean * mean;
    const float rstd = rsqrtf(var + 1e-5f);
    float ov[8];
    #pragma unroll
    for (int j = 0; j < 8; j++) {
        int col = lane * 8 + j;
        ov[j] = (xv[j] - mean) * rstd * g[col] + be[col];
    }
    *(float4*)&out32[(size_t)row * 512 + lane * 8]     = float4{ ov[0], ov[1], ov[2], ov[3] };
    *(float4*)&out32[(size_t)row * 512 + lane * 8 + 4] = float4{ ov[4], ov[5], ov[6], ov[7] };
    if constexpr (MODE == 0) {
        alignas(16) u16 tmp[8];
        #pragma unroll
        for (int j = 0; j < 8; j++) tmp[j] = f2bf(ov[j]);
        *(uint4*)&out16[(size_t)row * 512 + lane * 8] = *(uint4*)tmp;
    }
}

extern "C" void kernel_launch(void* const* d_in, const int* in_sizes, int n_in,
                              void* d_out, int out_size, void* d_ws, size_t ws_size,
                              hipStream_t stream) {
    const float* x      = (const float*)d_in[0];
    const float* y      = (const float*)d_in[1];
    const int*   x_mask = (const int*)d_in[2];
    const int*   y_mask = (const int*)d_in[3];
    const float* Wq  = (const float*)d_in[4];
    const float* bq  = (const float*)d_in[5];
    const float* Wk  = (const float*)d_in[6];
    const float* bk  = (const float*)d_in[7];
    const float* Wv  = (const float*)d_in[8];
    const float* bv  = (const float*)d_in[9];
    const float* Wo  = (const float*)d_in[10];
    const float* bo  = (const float*)d_in[11];
    const float* g1  = (const float*)d_in[12];
    const float* be1 = (const float*)d_in[13];
    const float* g2  = (const float*)d_in[14];
    const float* be2 = (const float*)d_in[15];
    const float* W1  = (const float*)d_in[16];
    const float* bf1 = (const float*)d_in[17];
    const float* W2  = (const float*)d_in[18];
    const float* bf2 = (const float*)d_in[19];

    char* p = (char*)d_ws;
    auto alloc = [&](size_t bytes) { char* r = p; p += (bytes + 255) & ~(size_t)255; return r; };
    u16*   x16   = (u16*)alloc(2097152ULL * 2);
    u16*   y16   = (u16*)alloc(2097152ULL * 2);
    u16*   wt    = (u16*)alloc(4718592ULL * 2);
    u16*   qkv   = (u16*)alloc(9ULL * 2097152 * 2);
    u16*   vt    = (u16*)alloc(2097152ULL * 2);
    u16*   obuf  = (u16*)alloc(2097152ULL * 2);
    float* xo    = (float*)alloc(2097152ULL * 4);
    float* h32   = (float*)alloc(2097152ULL * 4);
    u16*   h16   = (u16*)alloc(2097152ULL * 2);
    u16*   ffmid = (u16*)alloc(8388608ULL * 2);
    float* ffout = (float*)alloc(2097152ULL * 4);
    if ((size_t)(p - (char*)d_ws) > ws_size) return;  // ws too small: bail cleanly

    // 1) convert activations to bf16 (fused x+y)
    cvt2_kernel<<<4096, 256, 0, stream>>>(x, y, x16, y16);
    // 2) transpose+convert the 12 needed weight matrices (exact 4608-tile grid)
    wtrans_kernel<<<4608, dim3(32, 8), 0, stream>>>(Wq, Wk, Wv, Wo, W1, W2, wt);
    // 3) Q_l (scaled*log2e, masked), K_l (l=0..3), V_3 projections
    qkv_gemm_kernel<<<dim3(4, 32, 9), 256, 0, stream>>>(x16, y16, wt, qkv, bq, bk, bv, x_mask);
    // 4) per-head V transpose
    vtrans_kernel<<<dim3(16, 32), 256, 0, stream>>>(qkv + 8ULL * 2097152, vt);
    // 5) fused 4-layer residual attention (QB=64, grid 512, 8-wave blocks, Ps repack)
    attn_kernel<<<512, 512, 0, stream>>>(qkv, x_mask, y_mask, vt, obuf);
    // 6) o@Wo + bo + x -> xo (f32)   [BN=64 -> 256 blocks]
    gemm_bt_kernel<2, 1><<<dim3(8, 32), 256, 0, stream>>>(obuf, wt + 2359296, bo + 3 * 512, xo, x, 512, 512);
    // 7) LN1 -> h (f32 + bf16)
    ln_kernel<0><<<1024, 256, 0, stream>>>(xo, g1 + 3 * 512, be1 + 3 * 512, h32, h16);
    // 8) gelu(h@W1 + bf1) -> ffmid (bf16)   [BN=128 -> 512 blocks]
    gemm_bt_kernel<4, 2><<<dim3(16, 32), 256, 0, stream>>>(h16, wt + 2621440, bf1 + 3 * 2048, ffmid, nullptr, 2048, 512);
    // 9) ffmid@W2 + bf2 + h -> ffout (f32)   [BN=64 -> 256 blocks]
    gemm_bt_kernel<2, 1><<<dim3(8, 32), 256, 0, stream>>>(ffmid, wt + 3670016, bf2 + 3 * 512, ffout, h32, 512, 2048);
    // 10) LN2 -> d_out (f32)
    ln_kernel<1><<<1024, 256, 0, stream>>>(ffout, g2 + 3 * 512, be2 + 3 * 512, (float*)d_out, nullptr);
}

// Round 19
// 173.861 us; speedup vs baseline: 1.0690x; 1.0165x over previous
//
#include <hip/hip_runtime.h>
#include <cstdint>

using u16    = unsigned short;
using u32    = unsigned int;
using bf16x8 = __attribute__((ext_vector_type(8))) __bf16;
using f32x4  = __attribute__((ext_vector_type(4))) float;

__device__ __forceinline__ u16 f2bf(float f) {
    u32 u = __builtin_bit_cast(u32, f);
    u += 0x7FFFu + ((u >> 16) & 1u);
    return (u16)(u >> 16);
}
__device__ __forceinline__ float bf2f(u16 u) {
    return __builtin_bit_cast(float, (u32)u << 16);
}
__device__ __forceinline__ u32 pk_bf16(float a, float b) {
    u32 r;
    asm("v_cvt_pk_bf16_f32 %0, %1, %2" : "=v"(r) : "v"(a), "v"(b));
    return r;
}
// raw 2^x (v_exp_f32 IS exp2 in hardware; single TRANS op, no libm path)
__device__ __forceinline__ float hw_exp2(float x) {
    float r;
    asm("v_exp_f32 %0, %1" : "=v"(r) : "v"(x));
    return r;
}
__device__ __forceinline__ void load_lds16(const u16* g, u16* l) {
    __builtin_amdgcn_global_load_lds((const __attribute__((address_space(1))) void*)g,
                                     (__attribute__((address_space(3))) void*)l, 16, 0, 0);
}

// ---------------- fused f32 -> bf16 convert for x and y ----------------
__global__ __launch_bounds__(256) void cvt2_kernel(const float* __restrict__ a,
                                                   const float* __restrict__ b,
                                                   u16* __restrict__ oa,
                                                   u16* __restrict__ ob)
{
    const int bid = blockIdx.x;
    const float* in = bid < 2048 ? a : b;
    u16* out = bid < 2048 ? oa : ob;
    int i = ((bid & 2047) * 256 + threadIdx.x) * 4;
    float4 v = *(const float4*)(in + i);
    uint2 o;
    o.x = (u32)f2bf(v.x) | ((u32)f2bf(v.y) << 16);
    o.y = (u32)f2bf(v.z) | ((u32)f2bf(v.w) << 16);
    *(uint2*)(out + i) = o;
}

// ---------------- weight transpose + convert (flat exact grid: 4608 blocks) ----------------
__global__ __launch_bounds__(256) void wtrans_kernel(const float* __restrict__ Wq,
                                                     const float* __restrict__ Wk,
                                                     const float* __restrict__ Wv,
                                                     const float* __restrict__ Wo,
                                                     const float* __restrict__ W1,
                                                     const float* __restrict__ W2,
                                                     u16* __restrict__ wt)
{
    const int gid = blockIdx.x;
    const float* src; u16* dst; int K = 512, N = 512; int n0, k0;
    if (gid < 2560) {
        int z = gid >> 8, tid = gid & 255;
        switch (z) {
            case 0: case 1: case 2: case 3:
                src = Wq + (size_t)z * 262144;        dst = wt + (size_t)z * 262144;            break;
            case 4: case 5: case 6: case 7:
                src = Wk + (size_t)(z - 4) * 262144;  dst = wt + 1048576 + (size_t)(z - 4) * 262144; break;
            case 8: src = Wv + 3 * 262144;  dst = wt + 2097152; break;
            default: src = Wo + 3 * 262144; dst = wt + 2359296; break;
        }
        n0 = (tid & 15) * 32; k0 = (tid >> 4) * 32;
    } else if (gid < 3584) {
        int tid = gid - 2560;
        src = W1 + 3 * 1048576; dst = wt + 2621440; K = 512; N = 2048;
        n0 = (tid & 63) * 32; k0 = (tid >> 6) * 32;
    } else {
        int tid = gid - 3584;
        src = W2 + 3 * 1048576; dst = wt + 3670016; K = 2048; N = 512;
        n0 = (tid & 15) * 32; k0 = (tid >> 4) * 32;
    }
    __shared__ float tile[32][33];
    int tx = threadIdx.x, ty = threadIdx.y;
    #pragma unroll
    for (int i = 0; i < 4; i++) {
        int r = ty + i * 8;
        tile[r][tx] = src[(size_t)(k0 + r) * N + n0 + tx];
    }
    __syncthreads();
    #pragma unroll
    for (int i = 0; i < 4; i++) {
        int rn = ty + i * 8;
        dst[(size_t)(n0 + rn) * K + k0 + tx] = f2bf(tile[tx][rn]);
    }
}

// ---------------- BK=32 double-buffered GEMM core (m97 shape + 2-phase + XOR swizzle) ----------------
template<int BNF>
__device__ __forceinline__ void gemm_core32(const u16* __restrict__ A,
                                            const u16* __restrict__ BT,
                                            int K, int m0, int n0,
                                            u16 (*As)[32], u16 (*Bs)[32],
                                            f32x4 acc[4][BNF])
{
    const int t    = threadIdx.x;
    const int lane = t & 63, wid = t >> 6;
    const int wm = wid >> 1, wn = wid & 1;
    const int lrow = lane & 15, kg = lane >> 4;
    const int sr = lane >> 2;                              // row within a 16-row staging slab
    const int sg = ((lane & 3) ^ ((lane >> 3) & 3)) * 8;   // pre-swizzled source granule col

    auto stage = [&](int buf, int ks) {
        #pragma unroll
        for (int i = 0; i < 2; i++) {
            int row = wid * 32 + i * 16;
            load_lds16(&A[(size_t)(m0 + row + sr) * K + ks + sg], &As[buf * 128 + row][0]);
        }
        if constexpr (BNF == 4) {
            #pragma unroll
            for (int i = 0; i < 2; i++) {
                int row = wid * 32 + i * 16;
                load_lds16(&BT[(size_t)(n0 + row + sr) * K + ks + sg], &Bs[buf * 128 + row][0]);
            }
        } else {
            int row = wid * 16;
            load_lds16(&BT[(size_t)(n0 + row + sr) * K + ks + sg], &Bs[buf * 64 + row][0]);
        }
    };

    stage(0, 0);
    __syncthreads();
    int buf = 0;
    for (int ks = 0; ks < K; ks += 32) {
        if (ks + 32 < K) stage(buf ^ 1, ks + 32);
        const int rg = (kg ^ ((lrow >> 1) & 3)) * 8;       // swizzled read granule
        bf16x8 af[4], bfv[BNF];
        #pragma unroll
        for (int i = 0; i < 4; i++)
            af[i] = *(const bf16x8*)&As[buf * 128 + wm * 64 + i * 16 + lrow][rg];
        #pragma unroll
        for (int j = 0; j < BNF; j++)
            bfv[j] = *(const bf16x8*)&Bs[buf * (BNF * 32) + wn * (BNF * 16) + j * 16 + lrow][rg];
        #pragma unroll
        for (int i = 0; i < 4; i++)
            #pragma unroll
            for (int j = 0; j < BNF; j++)
                acc[i][j] = __builtin_amdgcn_mfma_f32_16x16x32_bf16(af[i], bfv[j], acc[i][j], 0, 0, 0);
        __syncthreads();
        buf ^= 1;
    }
}

// ---------------- batched QKV projection GEMM (z: 0-3 Q_l scaled+masked, 4-7 K_l, 8 V_3) ----------------
// Q pre-scale folds SCALE * log2(e): attn computes hw_exp2(s) == exp(s_raw * 0.125).
__global__ __launch_bounds__(256) void qkv_gemm_kernel(const u16* __restrict__ x16,
                                                       const u16* __restrict__ y16,
                                                       const u16* __restrict__ wt,
                                                       u16* __restrict__ qkv,
                                                       const float* __restrict__ bq,
                                                       const float* __restrict__ bk,
                                                       const float* __restrict__ bv,
                                                       const int* __restrict__ x_mask)
{
    __shared__ u16 As[256][32];
    __shared__ u16 Bs[256][32];
    const int z = blockIdx.z;
    const u16* A; const u16* BT; const float* bias;
    if (z < 4)      { A = x16; BT = wt + (size_t)z * 262144;                 bias = bq + z * 512; }
    else if (z < 8) { A = y16; BT = wt + 1048576 + (size_t)(z - 4) * 262144; bias = bk + (z - 4) * 512; }
    else            { A = y16; BT = wt + 2097152;                            bias = bv + 3 * 512; }
    u16* out = qkv + (size_t)z * 2097152;

    const int m0 = blockIdx.y * 128, n0 = blockIdx.x * 128;
    f32x4 acc[4][4];
    #pragma unroll
    for (int i = 0; i < 4; i++)
        #pragma unroll
        for (int j = 0; j < 4; j++) acc[i][j] = f32x4{0.f, 0.f, 0.f, 0.f};
    gemm_core32<4>(A, BT, 512, m0, n0, As, Bs, acc);

    const int lane = threadIdx.x & 63, wid = threadIdx.x >> 6;
    const int wm = wid >> 1, wn = wid & 1;
    const int lrow = lane & 15, kg = lane >> 4;
    #pragma unroll
    for (int i = 0; i < 4; i++)
        #pragma unroll
        for (int j = 0; j < 4; j++)
            #pragma unroll
            for (int r = 0; r < 4; r++) {
                int row = m0 + wm * 64 + i * 16 + kg * 4 + r;
                int col = n0 + wn * 64 + j * 16 + lrow;
                float v = acc[i][j][r] + bias[col];
                // 0.125 * log2(e)
                if (z < 4) v *= 0.180336880f * (x_mask[row] ? 1.f : 0.f);
                out[(size_t)row * 512 + col] = f2bf(v);
            }
}

// ---------------- generic GEMM with epilogue. EPI 1: f32 out + bias + residual; EPI 2: bf16 out + bias + exact GELU ----------------
template<int BNF, int EPI>
__global__ __launch_bounds__(256) void gemm_bt_kernel(const u16* __restrict__ A,
                                                      const u16* __restrict__ BT,
                                                      const float* __restrict__ bias,
                                                      void* __restrict__ outp,
                                                      const float* __restrict__ res,
                                                      int N, int K)
{
    __shared__ u16 As[256][32];
    __shared__ u16 Bs[BNF * 64][32];
    const int m0 = blockIdx.y * 128, n0 = blockIdx.x * (BNF * 32);
    f32x4 acc[4][BNF];
    #pragma unroll
    for (int i = 0; i < 4; i++)
        #pragma unroll
        for (int j = 0; j < BNF; j++) acc[i][j] = f32x4{0.f, 0.f, 0.f, 0.f};
    gemm_core32<BNF>(A, BT, K, m0, n0, As, Bs, acc);

    const int lane = threadIdx.x & 63, wid = threadIdx.x >> 6;
    const int wm = wid >> 1, wn = wid & 1;
    const int lrow = lane & 15, kg = lane >> 4;
    #pragma unroll
    for (int i = 0; i < 4; i++)
        #pragma unroll
        for (int j = 0; j < BNF; j++)
            #pragma unroll
            for (int r = 0; r < 4; r++) {
                int row = m0 + wm * 64 + i * 16 + kg * 4 + r;
                int col = n0 + wn * (BNF * 16) + j * 16 + lrow;
                float v = acc[i][j][r] + bias[col];
                if constexpr (EPI == 1) {
                    ((float*)outp)[(size_t)row * N + col] = v + res[(size_t)row * N + col];
                } else {
                    v = 0.5f * v * (1.f + erff(v * 0.70710678118654752f));
                    ((u16*)outp)[(size_t)row * N + col] = f2bf(v);
                }
            }
}

// ---------------- V transpose per head: v (b,h,m,d) -> vt (b,h,d,m) ----------------
__global__ __launch_bounds__(256) void vtrans_kernel(const u16* __restrict__ v, u16* __restrict__ vt)
{
    const int bh = blockIdx.y, m0 = blockIdx.x * 64;
    const int b = bh >> 3, h = bh & 7;
    const u16* src = v + (size_t)b * 524288 + (size_t)h * 65536;   // (1024 m, 64 d)
    u16* dst = vt + (size_t)bh * 65536;                            // (64 d, 1024 m)
    __shared__ u16 tile[64][72];
    const int t = threadIdx.x;
    #pragma unroll
    for (int i = 0; i < 2; i++) {
        int idx = t + i * 256, r = idx >> 3, q = idx & 7;
        *(uint4*)&tile[r][q * 8] = *(const uint4*)&src[(size_t)(m0 + r) * 64 + q * 8];
    }
    __syncthreads();
    #pragma unroll
    for (int i = 0; i < 2; i++) {
        int idx = t + i * 256, d = idx >> 3, q = idx & 7;
        alignas(16) u16 tmp[8];
        #pragma unroll
        for (int j = 0; j < 8; j++) tmp[j] = tile[q * 8 + j][d];
        *(uint4*)&dst[(size_t)d * 1024 + m0 + q * 8] = *(uint4*)tmp;
    }
}

// ---------------- fused 4-layer residual attention, 8-wave blocks, async-STAGE split ----------------
// r18 skeleton (passing, 57.8us) with ONE change (T14): K/V staged global->REG early,
// ds_write to LDS after compute. The vmcnt wait moves after the compute phase (latency
// hidden under QK/softmax/PV); the tile barrier now only orders cheap ds_writes.
// Same addressing: pre-swizzled global source, linear LDS dest (base + lane*8 u16).
__global__ __launch_bounds__(512) void attn_kernel(const u16* __restrict__ qkv,
                                                   const int* __restrict__ x_mask,
                                                   const int* __restrict__ y_mask,
                                                   const u16* __restrict__ vt,
                                                   u16* __restrict__ obuf)
{
    __shared__ __align__(16) char smem[65536];
    u16 (*Kb)[4][32][64] = reinterpret_cast<u16(*)[4][32][64]>(smem);        // [2][4][32][64] 32KB
    u16 (*Vb)[64][32]    = reinterpret_cast<u16(*)[64][32]>(smem + 32768);   // [2][64][32]    8KB
    float* ymb           = reinterpret_cast<float*>(smem + 40960);           // [1024]         4KB
    u16 (*Ps)[32][40]    = reinterpret_cast<u16(*)[32][40]>(smem + 45056);   // [8][32][40]    20KB
    u16 (*Osh)[32][72]   = reinterpret_cast<u16(*)[32][72]>(smem);           // overlay [8][32][72] 36KB

    const int t = threadIdx.x;
    const int wid = t >> 6, lane = t & 63;
    const int lrow = lane & 15, kg = lane >> 4;
    const int L  = wid & 3;        // layer
    const int qh = wid >> 2;       // q-half (0: rows 0-31, 1: rows 32-63)

    const int gid  = blockIdx.x;
    const int orig = (gid & 7) * 64 + (gid >> 3);
    const int bh = orig >> 4, qt = orig & 15;
    const int b = bh >> 3, h = bh & 7;
    const int q0 = qt * 64;

    const size_t headoff = (size_t)b * 524288 + (size_t)h * 65536;
    const u16* Q  = qkv + (size_t)L * 2097152 + headoff;
    const u16* VT = vt + (size_t)bh * 65536;

    for (int i = t; i < 1024; i += 512)
        ymb[i] = y_mask[b * 1024 + i] ? 0.f : -1e9f;

    // K: flat rows fr = i*64 + wid*8 + (lane>>3); fr&7 == lane>>3 -> same swizzle as r10.
    const int kscol = ((lane & 7) ^ (lane >> 3)) * 8;
    const int vsrow = wid * 16 + (lane >> 2);
    const int vscol = (((lane & 3) ^ ((vsrow & 3) ^ ((vsrow >> 2) & 3))) * 8);
    const int fswz  = (lrow & 3) ^ ((lrow >> 2) & 3);

    // per-lane K global sources (two slabs) and V source; LDS dests are linear.
    const int fr0 = wid * 8 + (lane >> 3);          // i=0: layers 0-1
    const int fr1 = 64 + fr0;                       // i=1: layers 2-3
    const u16* ksrc0 = qkv + (size_t)(4 + (fr0 >> 5)) * 2097152 + headoff + (size_t)(fr0 & 31) * 64 + kscol;
    const u16* ksrc1 = qkv + (size_t)(4 + (fr1 >> 5)) * 2097152 + headoff + (size_t)(fr1 & 31) * 64 + kscol;
    const u16* vsrc  = VT + (size_t)vsrow * 1024 + vscol;

    auto stage_load = [&](int mt, uint4& k0r, uint4& k1r, uint4& vr) {
        const int m0 = mt * 32;
        k0r = *(const uint4*)(ksrc0 + (size_t)m0 * 64);
        k1r = *(const uint4*)(ksrc1 + (size_t)m0 * 64);
        if (wid < 4) vr = *(const uint4*)(vsrc + m0);
    };
    auto stage_write = [&](int buf, const uint4& k0r, const uint4& k1r, const uint4& vr) {
        u16* kbase = &Kb[buf][0][0][0];
        *(uint4*)(kbase + (0 * 512 + wid * 64) * 8 + lane * 8) = k0r;
        *(uint4*)(kbase + (1 * 512 + wid * 64) * 8 + lane * 8) = k1r;
        if (wid < 4)
            *(uint4*)(&Vb[buf][wid * 16][0] + lane * 8) = vr;
    };

    bf16x8 aq[2][2];
    #pragma unroll
    for (int i = 0; i < 2; i++) {
        const int qr = q0 + qh * 32 + i * 16 + lrow;
        aq[i][0] = *(const bf16x8*)&Q[(size_t)qr * 64 + kg * 8];
        aq[i][1] = *(const bf16x8*)&Q[(size_t)qr * 64 + 32 + kg * 8];
    }
    float xmf[2];
    #pragma unroll
    for (int i = 0; i < 2; i++)
        xmf[i] = x_mask[b * 1024 + q0 + qh * 32 + i * 16 + lrow] ? 1.f : 0.f;

    f32x4 oacc[2][4];
    float psum[2] = {0.f, 0.f};
    #pragma unroll
    for (int i = 0; i < 2; i++)
        #pragma unroll
        for (int d = 0; d < 4; d++) oacc[i][d] = f32x4{0.f, 0.f, 0.f, 0.f};

    uint4 k0r, k1r, vr;
    stage_load(0, k0r, k1r, vr);
    stage_write(0, k0r, k1r, vr);
    __syncthreads();

    for (int mt = 0; mt < 32; mt++) {
        const int buf = mt & 1;
        const int m0 = mt * 32;
        if (mt < 31) stage_load(mt + 1, k0r, k1r, vr);   // VMEM issue only

        bf16x8 kb[2][2];
        #pragma unroll
        for (int nf = 0; nf < 2; nf++)
            #pragma unroll
            for (int kk = 0; kk < 2; kk++)
                kb[nf][kk] = *(const bf16x8*)&Kb[buf][L][nf * 16 + lrow][((kk * 4 + kg) ^ (lrow & 7)) * 8];

        float yb[2][4];
        #pragma unroll
        for (int nf = 0; nf < 2; nf++)
            #pragma unroll
            for (int r = 0; r < 4; r++) yb[nf][r] = ymb[m0 + nf * 16 + kg * 4 + r];

        // swapped QK^T -> hw exp2 -> pack P via per-wave Ps LDS (rows = q, cols = key)
        #pragma unroll
        for (int i = 0; i < 2; i++) {
            f32x4 s0 = f32x4{0.f, 0.f, 0.f, 0.f}, s1 = f32x4{0.f, 0.f, 0.f, 0.f};
            s0 = __builtin_amdgcn_mfma_f32_16x16x32_bf16(kb[0][0], aq[i][0], s0, 0, 0, 0);
            s0 = __builtin_amdgcn_mfma_f32_16x16x32_bf16(kb[0][1], aq[i][1], s0, 0, 0, 0);
            s1 = __builtin_amdgcn_mfma_f32_16x16x32_bf16(kb[1][0], aq[i][0], s1, 0, 0, 0);
            s1 = __builtin_amdgcn_mfma_f32_16x16x32_bf16(kb[1][1], aq[i][1], s1, 0, 0, 0);
            float p0 = hw_exp2(fmaf(xmf[i], yb[0][0], s0[0]));
            float p1 = hw_exp2(fmaf(xmf[i], yb[0][1], s0[1]));
            float p2 = hw_exp2(fmaf(xmf[i], yb[0][2], s0[2]));
            float p3 = hw_exp2(fmaf(xmf[i], yb[0][3], s0[3]));
            float p4 = hw_exp2(fmaf(xmf[i], yb[1][0], s1[0]));
            float p5 = hw_exp2(fmaf(xmf[i], yb[1][1], s1[1]));
            float p6 = hw_exp2(fmaf(xmf[i], yb[1][2], s1[2]));
            float p7 = hw_exp2(fmaf(xmf[i], yb[1][3], s1[3]));
            psum[i] += ((p0 + p1) + (p2 + p3)) + ((p4 + p5) + (p6 + p7));
            *(u32*)&Ps[wid][i * 16 + lrow][kg * 4]          = pk_bf16(p0, p1);
            *(u32*)&Ps[wid][i * 16 + lrow][kg * 4 + 2]      = pk_bf16(p2, p3);
            *(u32*)&Ps[wid][i * 16 + lrow][16 + kg * 4]     = pk_bf16(p4, p5);
            *(u32*)&Ps[wid][i * 16 + lrow][16 + kg * 4 + 2] = pk_bf16(p6, p7);
        }

        // PV: A-frags from Ps, B-frags from swizzled V tile
        bf16x8 pa[2], vbf[4];
        #pragma unroll
        for (int i = 0; i < 2; i++)
            pa[i] = *(const bf16x8*)&Ps[wid][i * 16 + lrow][kg * 8];
        #pragma unroll
        for (int d = 0; d < 4; d++)
            vbf[d] = *(const bf16x8*)&Vb[buf][d * 16 + lrow][(kg ^ fswz) * 8];
        #pragma unroll
        for (int i = 0; i < 2; i++)
            #pragma unroll
            for (int d = 0; d < 4; d++)
                oacc[i][d] = __builtin_amdgcn_mfma_f32_16x16x32_bf16(pa[i], vbf[d], oacc[i][d], 0, 0, 0);

        // write next tile to the other buffer AFTER compute (vmcnt wait lands here)
        if (mt < 31) stage_write(buf ^ 1, k0r, k1r, vr);
        __syncthreads();
    }

    #pragma unroll
    for (int i = 0; i < 2; i++) {
        psum[i] += __shfl_xor(psum[i], 16);
        psum[i] += __shfl_xor(psum[i], 32);
    }
    float invr[2][4];
    #pragma unroll
    for (int i = 0; i < 2; i++) {
        float inv = 1.f / psum[i];
        #pragma unroll
        for (int r = 0; r < 4; r++) invr[i][r] = __shfl(inv, kg * 4 + r, 16);
    }

    #pragma unroll
    for (int i = 0; i < 2; i++)
        #pragma unroll
        for (int d = 0; d < 4; d++)
            #pragma unroll
            for (int r = 0; r < 4; r++)
                Osh[wid][i * 16 + kg * 4 + r][d * 16 + lrow] = f2bf(oacc[i][d][r] * invr[i][r]);
    __syncthreads();

    // combine 4 layers: row64 = t>>3 (0..63), c0 = (t&7)*8; source wave = (row64>>5)*4 + l
    {
        const int row64 = t >> 3, c0 = (t & 7) * 8;
        const int wbase = (row64 >> 5) * 4, lr = row64 & 31;
        float a8[8] = {0, 0, 0, 0, 0, 0, 0, 0};
        #pragma unroll
        for (int l = 0; l < 4; l++) {
            uint4 v = *(const uint4*)&Osh[wbase + l][lr][c0];
            const u16* pv = (const u16*)&v;
            #pragma unroll
            for (int j = 0; j < 8; j++) a8[j] += bf2f(pv[j]);
        }
        alignas(16) u16 tmp[8];
        #pragma unroll
        for (int j = 0; j < 8; j++) tmp[j] = f2bf(a8[j]);
        *(uint4*)&obuf[(size_t)(b * 1024 + q0 + row64) * 512 + h * 64 + c0] = *(uint4*)tmp;
    }
}

// ---------------- LayerNorm (one wave per row of 512). MODE 0: write f32 + bf16; MODE 1: f32 only ----------------
template<int MODE>
__global__ __launch_bounds__(256) void ln_kernel(const float* __restrict__ in,
                                                 const float* __restrict__ g,
                                                 const float* __restrict__ be,
                                                 float* __restrict__ out32,
                                                 u16* __restrict__ out16)
{
    const int wid = threadIdx.x >> 6, lane = threadIdx.x & 63;
    const int row = blockIdx.x * 4 + wid;
    const float* x = in + (size_t)row * 512;
    float4 v1 = *(const float4*)&x[lane * 8];
    float4 v2 = *(const float4*)&x[lane * 8 + 4];
    float xv[8] = { v1.x, v1.y, v1.z, v1.w, v2.x, v2.y, v2.z, v2.w };
    float s = 0.f, s2 = 0.f;
    #pragma unroll
    for (int j = 0; j < 8; j++) { s += xv[j]; s2 += xv[j] * xv[j]; }
    #pragma unroll
    for (int off = 32; off > 0; off >>= 1) {
        s  += __shfl_xor(s, off, 64);
        s2 += __shfl_xor(s2, off, 64);
    }
    const float mean = s * (1.f / 512.f);
    const float var  = s2 * (1.f / 512.f) - mean * mean;
    const float rstd = rsqrtf(var + 1e-5f);
    float ov[8];
    #pragma unroll
    for (int j = 0; j < 8; j++) {
        int col = lane * 8 + j;
        ov[j] = (xv[j] - mean) * rstd * g[col] + be[col];
    }
    *(float4*)&out32[(size_t)row * 512 + lane * 8]     = float4{ ov[0], ov[1], ov[2], ov[3] };
    *(float4*)&out32[(size_t)row * 512 + lane * 8 + 4] = float4{ ov[4], ov[5], ov[6], ov[7] };
    if constexpr (MODE == 0) {
        alignas(16) u16 tmp[8];
        #pragma unroll
        for (int j = 0; j < 8; j++) tmp[j] = f2bf(ov[j]);
        *(uint4*)&out16[(size_t)row * 512 + lane * 8] = *(uint4*)tmp;
    }
}

extern "C" void kernel_launch(void* const* d_in, const int* in_sizes, int n_in,
                              void* d_out, int out_size, void* d_ws, size_t ws_size,
                              hipStream_t stream) {
    const float* x      = (const float*)d_in[0];
    const float* y      = (const float*)d_in[1];
    const int*   x_mask = (const int*)d_in[2];
    const int*   y_mask = (const int*)d_in[3];
    const float* Wq  = (const float*)d_in[4];
    const float* bq  = (const float*)d_in[5];
    const float* Wk  = (const float*)d_in[6];
    const float* bk  = (const float*)d_in[7];
    const float* Wv  = (const float*)d_in[8];
    const float* bv  = (const float*)d_in[9];
    const float* Wo  = (const float*)d_in[10];
    const float* bo  = (const float*)d_in[11];
    const float* g1  = (const float*)d_in[12];
    const float* be1 = (const float*)d_in[13];
    const float* g2  = (const float*)d_in[14];
    const float* be2 = (const float*)d_in[15];
    const float* W1  = (const float*)d_in[16];
    const float* bf1 = (const float*)d_in[17];
    const float* W2  = (const float*)d_in[18];
    const float* bf2 = (const float*)d_in[19];

    char* p = (char*)d_ws;
    auto alloc = [&](size_t bytes) { char* r = p; p += (bytes + 255) & ~(size_t)255; return r; };
    u16*   x16   = (u16*)alloc(2097152ULL * 2);
    u16*   y16   = (u16*)alloc(2097152ULL * 2);
    u16*   wt    = (u16*)alloc(4718592ULL * 2);
    u16*   qkv   = (u16*)alloc(9ULL * 2097152 * 2);
    u16*   vt    = (u16*)alloc(2097152ULL * 2);
    u16*   obuf  = (u16*)alloc(2097152ULL * 2);
    float* xo    = (float*)alloc(2097152ULL * 4);
    float* h32   = (float*)alloc(2097152ULL * 4);
    u16*   h16   = (u16*)alloc(2097152ULL * 2);
    u16*   ffmid = (u16*)alloc(8388608ULL * 2);
    float* ffout = (float*)alloc(2097152ULL * 4);
    if ((size_t)(p - (char*)d_ws) > ws_size) return;  // ws too small: bail cleanly

    // 1) convert activations to bf16 (fused x+y)
    cvt2_kernel<<<4096, 256, 0, stream>>>(x, y, x16, y16);
    // 2) transpose+convert the 12 needed weight matrices (exact 4608-tile grid)
    wtrans_kernel<<<4608, dim3(32, 8), 0, stream>>>(Wq, Wk, Wv, Wo, W1, W2, wt);
    // 3) Q_l (scaled*log2e, masked), K_l (l=0..3), V_3 projections
    qkv_gemm_kernel<<<dim3(4, 32, 9), 256, 0, stream>>>(x16, y16, wt, qkv, bq, bk, bv, x_mask);
    // 4) per-head V transpose
    vtrans_kernel<<<dim3(16, 32), 256, 0, stream>>>(qkv + 8ULL * 2097152, vt);
    // 5) fused 4-layer residual attention (QB=64, grid 512, 8-wave blocks, async-STAGE)
    attn_kernel<<<512, 512, 0, stream>>>(qkv, x_mask, y_mask, vt, obuf);
    // 6) o@Wo + bo + x -> xo (f32)   [BN=64 -> 256 blocks]
    gemm_bt_kernel<2, 1><<<dim3(8, 32), 256, 0, stream>>>(obuf, wt + 2359296, bo + 3 * 512, xo, x, 512, 512);
    // 7) LN1 -> h (f32 + bf16)
    ln_kernel<0><<<1024, 256, 0, stream>>>(xo, g1 + 3 * 512, be1 + 3 * 512, h32, h16);
    // 8) gelu(h@W1 + bf1) -> ffmid (bf16)   [BN=128 -> 512 blocks]
    gemm_bt_kernel<4, 2><<<dim3(16, 32), 256, 0, stream>>>(h16, wt + 2621440, bf1 + 3 * 2048, ffmid, nullptr, 2048, 512);
    // 9) ffmid@W2 + bf2 + h -> ffout (f32)   [BN=64 -> 256 blocks]
    gemm_bt_kernel<2, 1><<<dim3(8, 32), 256, 0, stream>>>(ffmid, wt + 3670016, bf2 + 3 * 512, ffout, h32, 512, 2048);
    // 10) LN2 -> d_out (f32)
    ln_kernel<1><<<1024, 256, 0, stream>>>(ffout, g2 + 3 * 512, be2 + 3 * 512, (float*)d_out, nullptr);
}